// Round 6
// baseline (678.330 us; speedup 1.0000x reference)
//
#include <hip/hip_runtime.h>
#include <stdint.h>

#define BB 4
#define CC 128
#define HH 128
#define WW 128
#define LL 19
#define SS 512
#define HP 132
#define NPIX (HH*WW)      // 16384
#define PCELLS (HP*HP)    // 17424
#define NCELL (BB*PCELLS) // 69696

typedef float f32x4 __attribute__((ext_vector_type(4)));
typedef __bf16 bf16x8 __attribute__((ext_vector_type(8)));
typedef short short8 __attribute__((ext_vector_type(8)));

#define AS1Q __attribute__((address_space(1)))
#define AS3Q __attribute__((address_space(3)))
#define MEMFENCE asm volatile("" ::: "memory")

__device__ __forceinline__ void gld16(const void* g, void* l){
  __builtin_amdgcn_global_load_lds((const AS1Q void*)g, (AS3Q void*)l, 16, 0, 0);
}

__device__ inline unsigned short f2bf(float v){
  unsigned u = __float_as_uint(v);
  return (unsigned short)((u + 0x7fffu + ((u >> 16) & 1u)) >> 16);
}
__device__ inline float bflo(unsigned u){ return __uint_as_float(u << 16); }
__device__ inline float bfhi(unsigned u){ return __uint_as_float(u & 0xffff0000u); }

// ---------------- instance-norm stats ----------------
__global__ void k_stats(const float* __restrict__ x, float* __restrict__ mean,
                        float* __restrict__ rstd){
  const int bc = blockIdx.x;
  const int t = threadIdx.x;
  const int w = t >> 6, lane = t & 63;
  const float4* xv = (const float4*)(x + (size_t)bc * NPIX);
  float s = 0.f, q = 0.f;
  for (int i = t; i < NPIX/4; i += 256){
    float4 v = xv[i];
    s += v.x + v.y + v.z + v.w;
    q += v.x*v.x + v.y*v.y + v.z*v.z + v.w*v.w;
  }
  #pragma unroll
  for (int off = 32; off; off >>= 1){ s += __shfl_down(s, off); q += __shfl_down(q, off); }
  __shared__ float ls[4], lq[4];
  if (lane == 0){ ls[w] = s; lq[w] = q; }
  __syncthreads();
  if (t == 0){
    float S = ls[0]+ls[1]+ls[2]+ls[3];
    float Q = lq[0]+lq[1]+lq[2]+lq[3];
    float mn = S * (1.f/16384.f);
    float var = Q * (1.f/16384.f) - mn*mn;
    mean[bc] = mn;
    rstd[bc] = rsqrtf(var + 1e-5f);
  }
}

// ---------------- padded label ids (border sentinel = 19) ----------------
__global__ void k_ids(const float* __restrict__ seg, int* __restrict__ ids){
  int idx = blockIdx.x*256 + threadIdx.x;
  if (idx >= NCELL) return;
  int b = idx / PCELLS; int rem = idx - b*PCELLS;
  int r = rem / HP;     int cp = rem - r*HP;
  int id = LL;
  if (r >= 2 && r <= 129 && cp >= 2 && cp <= 129){
    int p = (r-2)*WW + (cp-2);
    const float* sp = seg + (size_t)b*LL*NPIX + p;
    id = 0;
    for (int j = 0; j < LL; ++j){
      if (sp[(size_t)j*NPIX] > 0.5f){ id = j; break; }
    }
  }
  ids[idx] = id;
}

// ---------------- style FC: 76 blocks = (j, e-quarter); fcw read once -----
__global__ void k_fc(const float* __restrict__ style, const float* __restrict__ fcw,
                     const float* __restrict__ fcb, float* __restrict__ mu){
  const int j = blockIdx.x >> 2, part = blockIdx.x & 3;
  const int t = threadIdx.x, w = t >> 6, lane = t & 63;
  __shared__ float s_s[4][SS];
  for (int i = t; i < 4*SS; i += 256){
    int b = i >> 9, e = i & 511;
    s_s[b][e] = style[(size_t)(b*LL + j)*SS + e];
  }
  __syncthreads();
  for (int e = part*128 + w; e < part*128 + 128; e += 4){
    const float* row = fcw + ((size_t)(j*SS + e))*SS;
    float a0=0.f, a1=0.f, a2=0.f, a3=0.f;
    #pragma unroll
    for (int i = 0; i < 8; ++i){
      int d = lane + i*64; float rv = row[d];
      a0 += s_s[0][d]*rv; a1 += s_s[1][d]*rv;
      a2 += s_s[2][d]*rv; a3 += s_s[3][d]*rv;
    }
    #pragma unroll
    for (int off = 32; off; off >>= 1){
      a0 += __shfl_down(a0,off); a1 += __shfl_down(a1,off);
      a2 += __shfl_down(a2,off); a3 += __shfl_down(a3,off);
    }
    if (lane == 0){
      float fb = fcb[j*SS + e];
      mu[(size_t)(0*LL+j)*SS + e] = fmaxf(a0+fb, 0.f);
      mu[(size_t)(1*LL+j)*SS + e] = fmaxf(a1+fb, 0.f);
      mu[(size_t)(2*LL+j)*SS + e] = fmaxf(a2+fb, 0.f);
      mu[(size_t)(3*LL+j)*SS + e] = fmaxf(a3+fb, 0.f);
    }
  }
}

// ---------------- fused prep: w2t (6400) + ttab (1000) + w2 (12800) -------
__global__ void k_prep(const float* __restrict__ cgw, const float* __restrict__ cbw,
                       float* __restrict__ Wtg, float* __restrict__ Wtb,
                       const float* __restrict__ ssw, unsigned short* __restrict__ Tt,
                       const float* __restrict__ sgw, const float* __restrict__ sbw,
                       unsigned short* __restrict__ W2){
  int blk = blockIdx.x;
  if (blk < 6400){
    int idx = blk*256 + threadIdx.x;           // 128*25*512
    int e = idx & 511; int rest = idx >> 9;
    int c = rest / 25, d = rest - (rest/25)*25;
    size_t src = ((size_t)c*SS + e)*25 + d;
    Wtg[idx] = cgw[src];
    Wtb[idx] = cbw[src];
  } else if (blk < 7400){
    int idx = (blk-6400)*256 + threadIdx.x;    // 20*25*512
    if (idx < 20*25*SS){
      int s = idx & 511; int rest = idx >> 9;
      int j = rest / 25, d = rest - (rest/25)*25;
      float v = 0.f;
      if (j < LL) v = ssw[((size_t)s*LL + j)*25 + d];
      Tt[idx] = f2bf(v);
    }
  } else {
    int idx = (blk-7400)*256 + threadIdx.x;    // 256*12800, k: s-chunk major
    int cpr = idx / 12800; int k = idx - cpr*12800;
    int schunk = k / 800; int r800 = k - schunk*800;
    int tap = r800 >> 5;  int s_in = r800 & 31;
    int s = schunk*32 + s_in;
    const float* w = (cpr < 128) ? sgw : sbw;
    int c = cpr & 127;
    W2[idx] = f2bf(w[((size_t)c*SS + s)*25 + tap]);
  }
}

// ---------------- G table: wave-per-output coalesced dot ------------------
__global__ void k_gtab(const float* __restrict__ mu, const float* __restrict__ Wtg,
                       const float* __restrict__ Wtb, float2* __restrict__ G){
  const int blk = blockIdx.x;
  const int b = blk >> 7, c = blk & 127;
  const int t = threadIdx.x, w = t >> 6, lane = t & 63;
  __shared__ float mu_s[LL*SS];
  for (int i = t; i < LL*SS; i += 256) mu_s[i] = mu[(size_t)b*LL*SS + i];
  __syncthreads();
  for (int i = 0; i < 125; ++i){
    int o = i*4 + w;
    int j = o / 25, d = o - (o/25)*25;
    float ag = 0.f, ab = 0.f;
    if (j < LL){
      const float4* wg4 = (const float4*)(Wtg + ((size_t)c*25 + d)*SS);
      const float4* wb4 = (const float4*)(Wtb + ((size_t)c*25 + d)*SS);
      const float4* m4p = (const float4*)(mu_s + j*SS);
      #pragma unroll
      for (int rp = 0; rp < 2; ++rp){
        int e4 = rp*64 + lane;
        float4 m4 = m4p[e4];
        float4 wv = wg4[e4];
        ag += m4.x*wv.x + m4.y*wv.y + m4.z*wv.z + m4.w*wv.w;
        float4 wv2 = wb4[e4];
        ab += m4.x*wv2.x + m4.y*wv2.y + m4.z*wv2.z + m4.w*wv2.w;
      }
      #pragma unroll
      for (int off = 32; off; off >>= 1){ ag += __shfl_down(ag, off); ab += __shfl_down(ab, off); }
    }
    if (lane == 0) G[((size_t)(b*CC + c))*500 + o] = make_float2(ag, ab);
  }
}

// ---------------- actv: Tt slice cached in LDS (500 x 128ch, 272B stride) -
__global__ __launch_bounds__(256) void k_actv(
    const int* __restrict__ ids, const unsigned short* __restrict__ Tt,
    const float* __restrict__ ssb, int4* __restrict__ actv){
  __shared__ unsigned short Tl[500*136];       // 136000 B
  const int t = threadIdx.x, w = t >> 6, lane = t & 63;
  const int cs  = blockIdx.x & 3;              // channel slice (128 ch)
  const int cg0 = blockIdx.x >> 2;             // cell group (128 cells)
  for (int i = t; i < 8000; i += 256){         // 500 rows x 16 int4
    int row = i >> 4, sub = i & 15;
    int4 v = *(const int4*)(Tt + (size_t)row*512 + cs*128 + sub*8);
    *(int4*)(Tl + row*136 + sub*8) = v;
  }
  __syncthreads();
  const int chsub = lane & 15;                 // 8-ch group within slice
  const int csub  = lane >> 4;                 // cell within 4-pack
  float bias[8];
  #pragma unroll
  for (int i = 0; i < 8; ++i) bias[i] = ssb[cs*128 + chsub*8 + i];
  for (int it = 0; it < 8; ++it){
    int cell = cg0*128 + it*16 + w*4 + csub;
    if (cell >= NCELL) break;
    int b = cell / PCELLS; int rem = cell - b*PCELLS;
    int r = rem / HP;      int cp = rem - r*HP;
    int4 outv = {0,0,0,0};
    if (r >= 2 && r <= 129 && cp >= 2 && cp <= 129){
      float a[8];
      #pragma unroll
      for (int i = 0; i < 8; ++i) a[i] = bias[i];
      const int* idb = ids + b*PCELLS + (r-2)*HP + (cp-2);
      int idw[25];
      #pragma unroll
      for (int dy = 0; dy < 5; ++dy)
        #pragma unroll
        for (int dx = 0; dx < 5; ++dx) idw[dy*5+dx] = idb[dy*HP + dx];
      #pragma unroll
      for (int tap = 0; tap < 25; ++tap){
        int4 u = *(const int4*)(Tl + (idw[tap]*25 + tap)*136 + chsub*8);
        a[0] += bflo(u.x); a[1] += bfhi(u.x);
        a[2] += bflo(u.y); a[3] += bfhi(u.y);
        a[4] += bflo(u.z); a[5] += bfhi(u.z);
        a[6] += bflo(u.w); a[7] += bfhi(u.w);
      }
      outv.x = (int)((unsigned)f2bf(fmaxf(a[0],0.f)) | ((unsigned)f2bf(fmaxf(a[1],0.f)) << 16));
      outv.y = (int)((unsigned)f2bf(fmaxf(a[2],0.f)) | ((unsigned)f2bf(fmaxf(a[3],0.f)) << 16));
      outv.z = (int)((unsigned)f2bf(fmaxf(a[4],0.f)) | ((unsigned)f2bf(fmaxf(a[5],0.f)) << 16));
      outv.w = (int)((unsigned)f2bf(fmaxf(a[6],0.f)) | ((unsigned)f2bf(fmaxf(a[7],0.f)) << 16));
    }
    actv[(size_t)cell*64 + cs*16 + chsub] = outv;
  }
}

// ---------------- big conv: 2-stage register-pipelined phases -------------
// Per phase: {ds_read NEXT-phase frags; [vmcnt(N)]; barrier; stage gld16;
//             MFMA on PREV-phase frags (compiler inserts counted lgkmcnt)}
__global__ __launch_bounds__(512, 2) void k_conv(
    const unsigned short* __restrict__ actv,   // bf16 [B][132][132][512]
    const unsigned short* __restrict__ W2,     // bf16 [256][12800] (reordered K)
    unsigned short* __restrict__ spade)        // bf16 [B][256][128][128]
{
  __shared__ int4 lds4[131072/16];             // 128 KiB: 4 bufs x (A 16K + B 16K)
  char* ldsb = (char*)lds4;
  const int blk = blockIdx.x;
  const int b  = blk >> 6;
  const int y0 = (blk & 63) * 2;
  const int t  = threadIdx.x;
  const int lane = t & 63;
  const int w  = t >> 6;
  const int wr = w >> 2, wc = w & 3;
  const int li = lane & 15, q = lane >> 4;

  // staging: source pre-swizzle (verified R1-R4)
  const int lsub  = lane >> 2;
  const int s_src = (lane & 3) ^ ((lane >> 3) & 3);
  const bool isA  = (w < 4);
  const char* p0[4];
  int ldsrel[4];
  #pragma unroll
  for (int l = 0; l < 4; ++l){
    int row = (isA ? w : (w - 4)) * 64 + l*16 + lsub;
    if (isA){
      int y = y0 + (row >> 7), x = row & 127;
      p0[l] = (const char*)(actv + (((size_t)b*HP + y)*HP + x)*SS + s_src*8);
    } else {
      p0[l] = (const char*)(W2 + (size_t)row*12800 + s_src*8);
    }
    ldsrel[l] = w*4096 + l*1024 + lane*16;
  }

  auto stage_tt = [&](int tt){               // 4 loads/thread
    int schunk = tt / 25; int tap = tt - schunk*25;
    int dy = tap / 5, dx = tap - dy*5;
    size_t offA = ((size_t)(dy*HP + dx)*SS + (size_t)schunk*32) * 2;
    size_t off = isA ? offA : (size_t)tt * 64;
    char* base = ldsb + ((tt & 3) * 32768);
    #pragma unroll
    for (int l = 0; l < 4; ++l)
      gld16(p0[l] + off, base + ldsrel[l]);
  };

  f32x4 acc[8][4];
  #pragma unroll
  for (int m = 0; m < 8; ++m)
    #pragma unroll
    for (int n = 0; n < 4; ++n) acc[m][n] = (f32x4){0.f,0.f,0.f,0.f};

  const int swz  = (q ^ ((li >> 1) & 3)) * 16;
  const int arel = (wr*128 + li)*64 + swz;
  const int brel = 16384 + (wc*64 + li)*64 + swz;

  bf16x8 a03[4], a47[4], bv[4], a03n[4], bvn[4];

  // prologue: 3 tiles in flight; preload tile-0 E-fragments
  stage_tt(0); stage_tt(1); stage_tt(2);
  asm volatile("s_waitcnt vmcnt(8)" ::: "memory");   // tile 0 landed
  __builtin_amdgcn_s_barrier();
  MEMFENCE;
  #pragma unroll
  for (int m = 0; m < 4; ++m) a03[m] = *(const bf16x8*)(ldsb + arel + m*1024);
  #pragma unroll
  for (int n = 0; n < 4; ++n) bv[n]  = *(const bf16x8*)(ldsb + brel + n*1024);

  for (int T = 0; T < 400; ++T){
    const char* buf  = ldsb + ((T    ) & 3)*32768;
    const char* bufn = ldsb + ((T + 1) & 3)*32768;
    // ---- phase E: issue a47(T) reads; vmcnt; bar; stage T+3; MFMA a03 x bv
    #pragma unroll
    for (int m = 0; m < 4; ++m) a47[m] = *(const bf16x8*)(buf + arel + (m+4)*1024);
    MEMFENCE;
    if (T < 398)       asm volatile("s_waitcnt vmcnt(4)" ::: "memory");
    else if (T == 398) asm volatile("s_waitcnt vmcnt(0)" ::: "memory");
    __builtin_amdgcn_s_barrier();
    MEMFENCE;
    if (T <= 396) stage_tt(T + 3);
    MEMFENCE;
    __builtin_amdgcn_s_setprio(1);
    #pragma unroll
    for (int m = 0; m < 4; ++m)
      #pragma unroll
      for (int n = 0; n < 4; ++n)
        acc[m][n] = __builtin_amdgcn_mfma_f32_16x16x32_bf16(a03[m], bv[n], acc[m][n], 0, 0, 0);
    __builtin_amdgcn_s_setprio(0);
    MEMFENCE;
    // ---- phase O: issue next-tile a03n/bvn reads; bar; MFMA a47 x bv ----
    if (T <= 398){
      #pragma unroll
      for (int m = 0; m < 4; ++m) a03n[m] = *(const bf16x8*)(bufn + arel + m*1024);
      #pragma unroll
      for (int n = 0; n < 4; ++n) bvn[n]  = *(const bf16x8*)(bufn + brel + n*1024);
    }
    MEMFENCE;
    __builtin_amdgcn_s_barrier();
    MEMFENCE;
    __builtin_amdgcn_s_setprio(1);
    #pragma unroll
    for (int m = 0; m < 4; ++m)
      #pragma unroll
      for (int n = 0; n < 4; ++n)
        acc[m+4][n] = __builtin_amdgcn_mfma_f32_16x16x32_bf16(a47[m], bv[n], acc[m+4][n], 0, 0, 0);
    __builtin_amdgcn_s_setprio(0);
    MEMFENCE;
    // rotate next -> current (static indexing; compiler renames)
    #pragma unroll
    for (int m = 0; m < 4; ++m) a03[m] = a03n[m];
    #pragma unroll
    for (int n = 0; n < 4; ++n) bv[n] = bvn[n];
  }

  // epilogue: bf16 pack; D col=lane&15 -> c', D row -> pixel (4 contig)
  const int xq4 = (lane >> 4) << 2;
  const int cq  = wc*64 + (lane & 15);
  #pragma unroll
  for (int m = 0; m < 8; ++m){
    int p = wr*128 + m*16 + xq4;
    int y = y0 + (p >> 7), x = p & 127;
    #pragma unroll
    for (int n = 0; n < 4; ++n){
      int cp = cq + n*16;
      f32x4 v = acc[m][n];
      uint2 pk;
      pk.x = (unsigned)f2bf(v.x) | ((unsigned)f2bf(v.y) << 16);
      pk.y = (unsigned)f2bf(v.z) | ((unsigned)f2bf(v.w) << 16);
      *(uint2*)(spade + (((size_t)(b*256 + cp))*HH + y)*WW + x) = pk;
    }
  }
}

// ---------------- final: paired-pixel gather + blend + IN apply -----------
__global__ void k_final(const float* __restrict__ xin, const int* __restrict__ ids,
                        const float2* __restrict__ G, const unsigned short* __restrict__ spade,
                        const float* __restrict__ mean, const float* __restrict__ rstd,
                        const float* __restrict__ cgb, const float* __restrict__ cbb,
                        const float* __restrict__ sgb, const float* __restrict__ sbb,
                        const float* __restrict__ bgam, const float* __restrict__ bbet,
                        float* __restrict__ out){
  const int blk = blockIdx.x;
  const int b = blk >> 7, c = blk & 127;
  const int t = threadIdx.x;
  __shared__ float2 Gl2[500];                  // [tap][id] transposed
  for (int i = t; i < 500; i += 256){
    int j = i / 25, d = i - (i/25)*25;
    Gl2[d*20 + j] = G[((size_t)(b*CC + c))*500 + i];
  }
  __syncthreads();
  const float ga = 1.f/(1.f + __expf(-bgam[0]));
  const float ba = 1.f/(1.f + __expf(-bbet[0]));
  const float mn = mean[b*CC + c], rs = rstd[b*CC + c];
  const float cg = cgb[c], cb = cbb[c], sg = sgb[c], sb = sbb[c];
  const float* xp  = xin + (size_t)(b*CC + c)*NPIX;
  const unsigned short* spg = spade + (size_t)(b*256 + c)*NPIX;
  const unsigned short* spb = spade + (size_t)(b*256 + c + 128)*NPIX;
  float* op = out + (size_t)(b*CC + c)*NPIX;
  const int* idb = ids + b*PCELLS;
  for (int p2 = t; p2 < NPIX/2; p2 += 256){
    int p = p2*2;
    int y = p >> 7, x = p & 127;
    float ag0=0.f, ab0=0.f, ag1=0.f, ab1=0.f;
    #pragma unroll
    for (int dy = 0; dy < 5; ++dy){
      const int* row = idb + (y+dy)*HP + x;
      int idv[6];
      #pragma unroll
      for (int k = 0; k < 6; ++k) idv[k] = row[k];
      #pragma unroll
      for (int dx = 0; dx < 5; ++dx){
        float2 g0 = Gl2[(dy*5+dx)*20 + idv[dx]];
        float2 g1 = Gl2[(dy*5+dx)*20 + idv[dx+1]];
        ag0 += g0.x; ab0 += g0.y;
        ag1 += g1.x; ab1 += g1.y;
      }
    }
    unsigned sg2 = *(const unsigned*)(spg + p);
    unsigned sb2 = *(const unsigned*)(spb + p);
    float2 xv = *(const float2*)(xp + p);
    float gf0 = ga*(ag0 + cg) + (1.f - ga)*(bflo(sg2) + sg);
    float bf0 = ba*(ab0 + cb) + (1.f - ba)*(bflo(sb2) + sb);
    float gf1 = ga*(ag1 + cg) + (1.f - ga)*(bfhi(sg2) + sg);
    float bf1 = ba*(ab1 + cb) + (1.f - ba)*(bfhi(sb2) + sb);
    float2 ov;
    ov.x = (xv.x - mn)*rs*(1.f + gf0) + bf0;
    ov.y = (xv.y - mn)*rs*(1.f + gf1) + bf1;
    *(float2*)(op + p) = ov;
  }
}

extern "C" void kernel_launch(void* const* d_in, const int* in_sizes, int n_in,
                              void* d_out, int out_size, void* d_ws, size_t ws_size,
                              hipStream_t stream){
  const float* x    = (const float*)d_in[0];
  const float* seg  = (const float*)d_in[1];
  const float* sty  = (const float*)d_in[2];
  const float* fcw  = (const float*)d_in[3];
  const float* fcb  = (const float*)d_in[4];
  const float* cgw  = (const float*)d_in[5];
  const float* cgb  = (const float*)d_in[6];
  const float* cbw  = (const float*)d_in[7];
  const float* cbb  = (const float*)d_in[8];
  const float* ssw  = (const float*)d_in[9];
  const float* ssb  = (const float*)d_in[10];
  const float* sgw  = (const float*)d_in[11];
  const float* sgb  = (const float*)d_in[12];
  const float* sbw  = (const float*)d_in[13];
  const float* sbb  = (const float*)d_in[14];
  const float* bgam = (const float*)d_in[15];
  const float* bbet = (const float*)d_in[16];
  float* out = (float*)d_out;

  char* ws = (char*)d_ws;
  size_t o = 0;
  auto alloc = [&](size_t n){ size_t r = o; o = (o + n + 255) & ~(size_t)255; return r; };
  float* mean          = (float*)(ws + alloc(512*4));
  float* rstd          = (float*)(ws + alloc(512*4));
  int*   ids           = (int*)  (ws + alloc((size_t)NCELL*4));
  float* mu            = (float*)(ws + alloc((size_t)BB*LL*SS*4));
  float2* G            = (float2*)(ws + alloc((size_t)BB*CC*500*8));
  unsigned short* Tt   = (unsigned short*)(ws + alloc((size_t)20*25*SS*2));
  unsigned short* W2   = (unsigned short*)(ws + alloc((size_t)256*12800*2));
  unsigned short* actv = (unsigned short*)(ws + alloc((size_t)NCELL*SS*2));
  unsigned short* spade= (unsigned short*)(ws + alloc((size_t)BB*256*NPIX*2 < (size_t)2*128*25*512*4
                                                      ? (size_t)2*128*25*512*4
                                                      : (size_t)BB*256*NPIX*2));
  // Wt tables alias spade region (consumed by k_gtab before k_conv writes it)
  float* Wtg = (float*)spade;
  float* Wtb = (float*)spade + (size_t)128*25*512;
  (void)o; (void)ws_size; (void)in_sizes; (void)n_in; (void)out_size; (void)sty;

  k_stats<<<dim3(512),  dim3(256), 0, stream>>>(x, mean, rstd);
  k_ids  <<<dim3(273),  dim3(256), 0, stream>>>(seg, ids);
  k_fc   <<<dim3(76),   dim3(256), 0, stream>>>(sty, fcw, fcb, mu);
  k_prep <<<dim3(20200),dim3(256), 0, stream>>>(cgw, cbw, Wtg, Wtb, ssw, Tt, sgw, sbw, W2);
  k_gtab <<<dim3(512),  dim3(256), 0, stream>>>(mu, Wtg, Wtb, G);
  k_actv <<<dim3(2180), dim3(256), 0, stream>>>(ids, Tt, ssb, (int4*)actv);
  k_conv <<<dim3(256),  dim3(512), 0, stream>>>(actv, W2, spade);
  k_final<<<dim3(512),  dim3(256), 0, stream>>>(x, ids, G, spade, mean, rstd,
                                                cgb, cbb, sgb, sbb, bgam, bbet, out);
}

// Round 7
// 644.636 us; speedup vs baseline: 1.0523x; 1.0523x over previous
//
#include <hip/hip_runtime.h>
#include <stdint.h>

#define BB 4
#define CC 128
#define HH 128
#define WW 128
#define LL 19
#define SS 512
#define HP 132
#define NPIX (HH*WW)      // 16384
#define PCELLS (HP*HP)    // 17424
#define NCELL (BB*PCELLS) // 69696

typedef float f32x4 __attribute__((ext_vector_type(4)));
typedef __bf16 bf16x8 __attribute__((ext_vector_type(8)));

#define AS1Q __attribute__((address_space(1)))
#define AS3Q __attribute__((address_space(3)))
#define MEMFENCE asm volatile("" ::: "memory")

__device__ __forceinline__ void gld16(const void* g, void* l){
  __builtin_amdgcn_global_load_lds((const AS1Q void*)g, (AS3Q void*)l, 16, 0, 0);
}

__device__ inline unsigned short f2bf(float v){
  unsigned u = __float_as_uint(v);
  return (unsigned short)((u + 0x7fffu + ((u >> 16) & 1u)) >> 16);
}
__device__ inline float bflo(unsigned u){ return __uint_as_float(u << 16); }
__device__ inline float bfhi(unsigned u){ return __uint_as_float(u & 0xffff0000u); }

// ------- fused pre-pass: stats (512) | ids (273) | fc (76) | prep (20200) --
__global__ void k_pre(const float* __restrict__ x, float* __restrict__ mean,
                      float* __restrict__ rstd,
                      const float* __restrict__ seg, int* __restrict__ ids,
                      const float* __restrict__ style, const float* __restrict__ fcw,
                      const float* __restrict__ fcb, float* __restrict__ mu,
                      const float* __restrict__ cgw, const float* __restrict__ cbw,
                      float* __restrict__ Wtg, float* __restrict__ Wtb,
                      const float* __restrict__ ssw, unsigned short* __restrict__ Tt,
                      const float* __restrict__ sgw, const float* __restrict__ sbw,
                      unsigned short* __restrict__ W2){
  __shared__ float shmem[4*SS];
  const int blk = blockIdx.x;
  const int t = threadIdx.x;
  if (blk < 512){
    // ---- instance-norm stats ----
    const int bc = blk;
    const int w = t >> 6, lane = t & 63;
    const float4* xv = (const float4*)(x + (size_t)bc * NPIX);
    float s = 0.f, q = 0.f;
    for (int i = t; i < NPIX/4; i += 256){
      float4 v = xv[i];
      s += v.x + v.y + v.z + v.w;
      q += v.x*v.x + v.y*v.y + v.z*v.z + v.w*v.w;
    }
    #pragma unroll
    for (int off = 32; off; off >>= 1){ s += __shfl_down(s, off); q += __shfl_down(q, off); }
    if (lane == 0){ shmem[w] = s; shmem[4 + w] = q; }
    __syncthreads();
    if (t == 0){
      float S = shmem[0]+shmem[1]+shmem[2]+shmem[3];
      float Q = shmem[4]+shmem[5]+shmem[6]+shmem[7];
      float mn = S * (1.f/16384.f);
      float var = Q * (1.f/16384.f) - mn*mn;
      mean[bc] = mn;
      rstd[bc] = rsqrtf(var + 1e-5f);
    }
  } else if (blk < 785){
    // ---- padded label ids (border sentinel = 19) ----
    int idx = (blk - 512)*256 + t;
    if (idx >= NCELL) return;
    int b = idx / PCELLS; int rem = idx - b*PCELLS;
    int r = rem / HP;     int cp = rem - r*HP;
    int id = LL;
    if (r >= 2 && r <= 129 && cp >= 2 && cp <= 129){
      int p = (r-2)*WW + (cp-2);
      const float* sp = seg + (size_t)b*LL*NPIX + p;
      id = 0;
      for (int j = 0; j < LL; ++j){
        if (sp[(size_t)j*NPIX] > 0.5f){ id = j; break; }
      }
    }
    ids[idx] = id;
  } else if (blk < 861){
    // ---- style FC: (j, e-quarter) ----
    const int jb = blk - 785;
    const int j = jb >> 2, part = jb & 3;
    const int w = t >> 6, lane = t & 63;
    float (*s_s)[SS] = (float(*)[SS])shmem;
    for (int i = t; i < 4*SS; i += 256){
      int b = i >> 9, e = i & 511;
      s_s[b][e] = style[(size_t)(b*LL + j)*SS + e];
    }
    __syncthreads();
    for (int e = part*128 + w; e < part*128 + 128; e += 4){
      const float* row = fcw + ((size_t)(j*SS + e))*SS;
      float a0=0.f, a1=0.f, a2=0.f, a3=0.f;
      #pragma unroll
      for (int i = 0; i < 8; ++i){
        int d = lane + i*64; float rv = row[d];
        a0 += s_s[0][d]*rv; a1 += s_s[1][d]*rv;
        a2 += s_s[2][d]*rv; a3 += s_s[3][d]*rv;
      }
      #pragma unroll
      for (int off = 32; off; off >>= 1){
        a0 += __shfl_down(a0,off); a1 += __shfl_down(a1,off);
        a2 += __shfl_down(a2,off); a3 += __shfl_down(a3,off);
      }
      if (lane == 0){
        float fb = fcb[j*SS + e];
        mu[(size_t)(0*LL+j)*SS + e] = fmaxf(a0+fb, 0.f);
        mu[(size_t)(1*LL+j)*SS + e] = fmaxf(a1+fb, 0.f);
        mu[(size_t)(2*LL+j)*SS + e] = fmaxf(a2+fb, 0.f);
        mu[(size_t)(3*LL+j)*SS + e] = fmaxf(a3+fb, 0.f);
      }
    }
  } else {
    // ---- prep: w2t (6400) | ttab (1000) | w2 (12800) ----
    int pb = blk - 861;
    if (pb < 6400){
      int idx = pb*256 + t;                      // 128*25*512
      int e = idx & 511; int rest = idx >> 9;
      int c = rest / 25, d = rest - (rest/25)*25;
      size_t src = ((size_t)c*SS + e)*25 + d;
      Wtg[idx] = cgw[src];
      Wtb[idx] = cbw[src];
    } else if (pb < 7400){
      int idx = (pb-6400)*256 + t;               // 20*25*512
      if (idx < 20*25*SS){
        int s = idx & 511; int rest = idx >> 9;
        int j = rest / 25, d = rest - (rest/25)*25;
        float v = 0.f;
        if (j < LL) v = ssw[((size_t)s*LL + j)*25 + d];
        Tt[idx] = f2bf(v);
      }
    } else {
      int idx = (pb-7400)*256 + t;               // 256*12800, k: s-chunk major
      int cpr = idx / 12800; int k = idx - cpr*12800;
      int schunk = k / 800; int r800 = k - schunk*800;
      int tap = r800 >> 5;  int s_in = r800 & 31;
      int s = schunk*32 + s_in;
      const float* w = (cpr < 128) ? sgw : sbw;
      int c = cpr & 127;
      W2[idx] = f2bf(w[((size_t)c*SS + s)*25 + tap]);
    }
  }
}

// ---------------- G table: wave-per-output coalesced dot ------------------
__global__ void k_gtab(const float* __restrict__ mu, const float* __restrict__ Wtg,
                       const float* __restrict__ Wtb, float2* __restrict__ G){
  const int blk = blockIdx.x;
  const int b = blk >> 7, c = blk & 127;
  const int t = threadIdx.x, w = t >> 6, lane = t & 63;
  __shared__ float mu_s[LL*SS];
  for (int i = t; i < LL*SS; i += 256) mu_s[i] = mu[(size_t)b*LL*SS + i];
  __syncthreads();
  for (int i = 0; i < 125; ++i){
    int o = i*4 + w;
    int j = o / 25, d = o - (o/25)*25;
    float ag = 0.f, ab = 0.f;
    if (j < LL){
      const float4* wg4 = (const float4*)(Wtg + ((size_t)c*25 + d)*SS);
      const float4* wb4 = (const float4*)(Wtb + ((size_t)c*25 + d)*SS);
      const float4* m4p = (const float4*)(mu_s + j*SS);
      #pragma unroll
      for (int rp = 0; rp < 2; ++rp){
        int e4 = rp*64 + lane;
        float4 m4 = m4p[e4];
        float4 wv = wg4[e4];
        ag += m4.x*wv.x + m4.y*wv.y + m4.z*wv.z + m4.w*wv.w;
        float4 wv2 = wb4[e4];
        ab += m4.x*wv2.x + m4.y*wv2.y + m4.z*wv2.z + m4.w*wv2.w;
      }
      #pragma unroll
      for (int off = 32; off; off >>= 1){ ag += __shfl_down(ag, off); ab += __shfl_down(ab, off); }
    }
    if (lane == 0) G[((size_t)(b*CC + c))*500 + o] = make_float2(ag, ab);
  }
}

// ---------------- actv: Tt slice cached in LDS (500 x 128ch, 272B stride) -
__global__ __launch_bounds__(256) void k_actv(
    const int* __restrict__ ids, const unsigned short* __restrict__ Tt,
    const float* __restrict__ ssb, int4* __restrict__ actv){
  __shared__ unsigned short Tl[500*136];       // 136000 B
  const int t = threadIdx.x, w = t >> 6, lane = t & 63;
  const int cs  = blockIdx.x & 3;              // channel slice (128 ch)
  const int cg0 = blockIdx.x >> 2;             // cell group (128 cells)
  for (int i = t; i < 8000; i += 256){         // 500 rows x 16 int4
    int row = i >> 4, sub = i & 15;
    int4 v = *(const int4*)(Tt + (size_t)row*512 + cs*128 + sub*8);
    *(int4*)(Tl + row*136 + sub*8) = v;
  }
  __syncthreads();
  const int chsub = lane & 15;                 // 8-ch group within slice
  const int csub  = lane >> 4;                 // cell within 4-pack
  float bias[8];
  #pragma unroll
  for (int i = 0; i < 8; ++i) bias[i] = ssb[cs*128 + chsub*8 + i];
  for (int it = 0; it < 8; ++it){
    int cell = cg0*128 + it*16 + w*4 + csub;
    if (cell >= NCELL) break;
    int b = cell / PCELLS; int rem = cell - b*PCELLS;
    int r = rem / HP;      int cp = rem - r*HP;
    int4 outv = {0,0,0,0};
    if (r >= 2 && r <= 129 && cp >= 2 && cp <= 129){
      float a[8];
      #pragma unroll
      for (int i = 0; i < 8; ++i) a[i] = bias[i];
      const int* idb = ids + b*PCELLS + (r-2)*HP + (cp-2);
      int idw[25];
      #pragma unroll
      for (int dy = 0; dy < 5; ++dy)
        #pragma unroll
        for (int dx = 0; dx < 5; ++dx) idw[dy*5+dx] = idb[dy*HP + dx];
      #pragma unroll
      for (int tap = 0; tap < 25; ++tap){
        int4 u = *(const int4*)(Tl + (idw[tap]*25 + tap)*136 + chsub*8);
        a[0] += bflo(u.x); a[1] += bfhi(u.x);
        a[2] += bflo(u.y); a[3] += bfhi(u.y);
        a[4] += bflo(u.z); a[5] += bfhi(u.z);
        a[6] += bflo(u.w); a[7] += bfhi(u.w);
      }
      outv.x = (int)((unsigned)f2bf(fmaxf(a[0],0.f)) | ((unsigned)f2bf(fmaxf(a[1],0.f)) << 16));
      outv.y = (int)((unsigned)f2bf(fmaxf(a[2],0.f)) | ((unsigned)f2bf(fmaxf(a[3],0.f)) << 16));
      outv.z = (int)((unsigned)f2bf(fmaxf(a[4],0.f)) | ((unsigned)f2bf(fmaxf(a[5],0.f)) << 16));
      outv.w = (int)((unsigned)f2bf(fmaxf(a[6],0.f)) | ((unsigned)f2bf(fmaxf(a[7],0.f)) << 16));
    }
    actv[(size_t)cell*64 + cs*16 + chsub] = outv;
  }
}

// ---------------- big conv: 1 barrier/step, unroll-2 ping-pong ------------
__global__ __launch_bounds__(512, 2) void k_conv(
    const unsigned short* __restrict__ actv,   // bf16 [B][132][132][512]
    const unsigned short* __restrict__ W2,     // bf16 [256][12800] (reordered K)
    unsigned short* __restrict__ spade)        // bf16 [B][256][128][128]
{
  __shared__ int4 lds4[131072/16];             // 128 KiB: 4 bufs x (A 16K + B 16K)
  char* ldsb = (char*)lds4;
  const int blk = blockIdx.x;
  const int b  = blk >> 6;
  const int y0 = (blk & 63) * 2;
  const int t  = threadIdx.x;
  const int lane = t & 63;
  const int w  = t >> 6;
  const int wr = w >> 2, wc = w & 3;
  const int li = lane & 15, q = lane >> 4;

  // staging: source pre-swizzle (verified R1-R5)
  const int lsub  = lane >> 2;
  const int s_src = (lane & 3) ^ ((lane >> 3) & 3);
  const bool isA  = (w < 4);
  const char* p0[4];
  int ldsrel[4];
  #pragma unroll
  for (int l = 0; l < 4; ++l){
    int row = (isA ? w : (w - 4)) * 64 + l*16 + lsub;
    if (isA){
      int y = y0 + (row >> 7), x = row & 127;
      p0[l] = (const char*)(actv + (((size_t)b*HP + y)*HP + x)*SS + s_src*8);
    } else {
      p0[l] = (const char*)(W2 + (size_t)row*12800 + s_src*8);
    }
    ldsrel[l] = w*4096 + l*1024 + lane*16;
  }

  auto stage_tt = [&](int tt){               // 4 loads/thread
    int schunk = tt / 25; int tap = tt - schunk*25;
    int dy = tap / 5, dx = tap - dy*5;
    size_t offA = ((size_t)(dy*HP + dx)*SS + (size_t)schunk*32) * 2;
    size_t off = isA ? offA : (size_t)tt * 64;
    char* base = ldsb + ((tt & 3) * 32768);
    #pragma unroll
    for (int l = 0; l < 4; ++l)
      gld16(p0[l] + off, base + ldsrel[l]);
  };

  f32x4 acc[8][4];
  #pragma unroll
  for (int m = 0; m < 8; ++m)
    #pragma unroll
    for (int n = 0; n < 4; ++n) acc[m][n] = (f32x4){0.f,0.f,0.f,0.f};

  const int swz  = (q ^ ((li >> 1) & 3)) * 16;
  const int arel = (wr*128 + li)*64 + swz;
  const int brel = 16384 + (wc*64 + li)*64 + swz;

  bf16x8 a03[2][4], bv[2][4], a47[4];

  // prologue: 3 tiles in flight; preload tile-0 low fragments
  stage_tt(0); stage_tt(1); stage_tt(2);
  asm volatile("s_waitcnt vmcnt(8)" ::: "memory");   // tile 0 landed
  __builtin_amdgcn_s_barrier();
  MEMFENCE;
  #pragma unroll
  for (int m = 0; m < 4; ++m) a03[0][m] = *(const bf16x8*)(ldsb + arel + m*1024);
  #pragma unroll
  for (int n = 0; n < 4; ++n) bv[0][n]  = *(const bf16x8*)(ldsb + brel + n*1024);

  // main: T = 0..397, single barrier per step, counted vmcnt(4)
  for (int T2 = 0; T2 < 199; ++T2){
    #pragma unroll
    for (int half = 0; half < 2; ++half){
      const int T = 2*T2 + half;
      const char* buf  = ldsb + ((unsigned)T & 3u)*32768;
      const char* bufn = ldsb + ((unsigned)(T+1) & 3u)*32768;
      const int cur = half, nxt = half ^ 1;
      #pragma unroll
      for (int m = 0; m < 4; ++m) a47[m] = *(const bf16x8*)(buf + arel + (m+4)*1024);
      MEMFENCE;
      asm volatile("s_waitcnt vmcnt(4)" ::: "memory");
      __builtin_amdgcn_s_barrier();
      MEMFENCE;
      if (T <= 396) stage_tt(T + 3);
      MEMFENCE;
      __builtin_amdgcn_s_setprio(1);
      #pragma unroll
      for (int m = 0; m < 4; ++m)
        #pragma unroll
        for (int n = 0; n < 4; ++n)
          acc[m][n] = __builtin_amdgcn_mfma_f32_16x16x32_bf16(a03[cur][m], bv[cur][n], acc[m][n], 0, 0, 0);
      __builtin_amdgcn_s_setprio(0);
      MEMFENCE;
      #pragma unroll
      for (int m = 0; m < 4; ++m) a03[nxt][m] = *(const bf16x8*)(bufn + arel + m*1024);
      #pragma unroll
      for (int n = 0; n < 4; ++n) bv[nxt][n]  = *(const bf16x8*)(bufn + brel + n*1024);
      MEMFENCE;
      __builtin_amdgcn_s_setprio(1);
      #pragma unroll
      for (int m = 0; m < 4; ++m)
        #pragma unroll
        for (int n = 0; n < 4; ++n)
          acc[m+4][n] = __builtin_amdgcn_mfma_f32_16x16x32_bf16(a47[m], bv[cur][n], acc[m+4][n], 0, 0, 0);
      __builtin_amdgcn_s_setprio(0);
      MEMFENCE;
    }
  }
  // T = 398 (set 0 holds tile 398)
  {
    const char* buf  = ldsb + (398 & 3)*32768;
    const char* bufn = ldsb + (399 & 3)*32768;
    #pragma unroll
    for (int m = 0; m < 4; ++m) a47[m] = *(const bf16x8*)(buf + arel + (m+4)*1024);
    MEMFENCE;
    asm volatile("s_waitcnt vmcnt(0)" ::: "memory");
    __builtin_amdgcn_s_barrier();
    MEMFENCE;
    #pragma unroll
    for (int m = 0; m < 4; ++m)
      #pragma unroll
      for (int n = 0; n < 4; ++n)
        acc[m][n] = __builtin_amdgcn_mfma_f32_16x16x32_bf16(a03[0][m], bv[0][n], acc[m][n], 0, 0, 0);
    #pragma unroll
    for (int m = 0; m < 4; ++m) a03[1][m] = *(const bf16x8*)(bufn + arel + m*1024);
    #pragma unroll
    for (int n = 0; n < 4; ++n) bv[1][n]  = *(const bf16x8*)(bufn + brel + n*1024);
    #pragma unroll
    for (int m = 0; m < 4; ++m)
      #pragma unroll
      for (int n = 0; n < 4; ++n)
        acc[m+4][n] = __builtin_amdgcn_mfma_f32_16x16x32_bf16(a47[m], bv[0][n], acc[m+4][n], 0, 0, 0);
  }
  // T = 399 (set 1 holds tile 399)
  {
    const char* buf = ldsb + (399 & 3)*32768;
    #pragma unroll
    for (int m = 0; m < 4; ++m) a47[m] = *(const bf16x8*)(buf + arel + (m+4)*1024);
    #pragma unroll
    for (int m = 0; m < 4; ++m)
      #pragma unroll
      for (int n = 0; n < 4; ++n)
        acc[m][n] = __builtin_amdgcn_mfma_f32_16x16x32_bf16(a03[1][m], bv[1][n], acc[m][n], 0, 0, 0);
    #pragma unroll
    for (int m = 0; m < 4; ++m)
      #pragma unroll
      for (int n = 0; n < 4; ++n)
        acc[m+4][n] = __builtin_amdgcn_mfma_f32_16x16x32_bf16(a47[m], bv[1][n], acc[m+4][n], 0, 0, 0);
  }

  // epilogue: bf16 pack; D col=lane&15 -> c', D row -> pixel (4 contig)
  const int xq4 = (lane >> 4) << 2;
  const int cq  = wc*64 + (lane & 15);
  #pragma unroll
  for (int m = 0; m < 8; ++m){
    int p = wr*128 + m*16 + xq4;
    int y = y0 + (p >> 7), x = p & 127;
    #pragma unroll
    for (int n = 0; n < 4; ++n){
      int cp = cq + n*16;
      f32x4 v = acc[m][n];
      uint2 pk;
      pk.x = (unsigned)f2bf(v.x) | ((unsigned)f2bf(v.y) << 16);
      pk.y = (unsigned)f2bf(v.z) | ((unsigned)f2bf(v.w) << 16);
      *(uint2*)(spade + (((size_t)(b*256 + cp))*HH + y)*WW + x) = pk;
    }
  }
}

// ---------------- final: paired-pixel gather + blend + IN apply -----------
__global__ void k_final(const float* __restrict__ xin, const int* __restrict__ ids,
                        const float2* __restrict__ G, const unsigned short* __restrict__ spade,
                        const float* __restrict__ mean, const float* __restrict__ rstd,
                        const float* __restrict__ cgb, const float* __restrict__ cbb,
                        const float* __restrict__ sgb, const float* __restrict__ sbb,
                        const float* __restrict__ bgam, const float* __restrict__ bbet,
                        float* __restrict__ out){
  const int blk = blockIdx.x;
  const int b = blk >> 7, c = blk & 127;
  const int t = threadIdx.x;
  __shared__ float2 Gl2[500];                  // [tap][id] transposed
  for (int i = t; i < 500; i += 256){
    int j = i / 25, d = i - (i/25)*25;
    Gl2[d*20 + j] = G[((size_t)(b*CC + c))*500 + i];
  }
  __syncthreads();
  const float ga = 1.f/(1.f + __expf(-bgam[0]));
  const float ba = 1.f/(1.f + __expf(-bbet[0]));
  const float mn = mean[b*CC + c], rs = rstd[b*CC + c];
  const float cg = cgb[c], cb = cbb[c], sg = sgb[c], sb = sbb[c];
  const float* xp  = xin + (size_t)(b*CC + c)*NPIX;
  const unsigned short* spg = spade + (size_t)(b*256 + c)*NPIX;
  const unsigned short* spb = spade + (size_t)(b*256 + c + 128)*NPIX;
  float* op = out + (size_t)(b*CC + c)*NPIX;
  const int* idb = ids + b*PCELLS;
  for (int p2 = t; p2 < NPIX/2; p2 += 256){
    int p = p2*2;
    int y = p >> 7, x = p & 127;
    float ag0=0.f, ab0=0.f, ag1=0.f, ab1=0.f;
    #pragma unroll
    for (int dy = 0; dy < 5; ++dy){
      const int* row = idb + (y+dy)*HP + x;
      int idv[6];
      #pragma unroll
      for (int k = 0; k < 6; ++k) idv[k] = row[k];
      #pragma unroll
      for (int dx = 0; dx < 5; ++dx){
        float2 g0 = Gl2[(dy*5+dx)*20 + idv[dx]];
        float2 g1 = Gl2[(dy*5+dx)*20 + idv[dx+1]];
        ag0 += g0.x; ab0 += g0.y;
        ag1 += g1.x; ab1 += g1.y;
      }
    }
    unsigned sg2 = *(const unsigned*)(spg + p);
    unsigned sb2 = *(const unsigned*)(spb + p);
    float2 xv = *(const float2*)(xp + p);
    float gf0 = ga*(ag0 + cg) + (1.f - ga)*(bflo(sg2) + sg);
    float bf0 = ba*(ab0 + cb) + (1.f - ba)*(bflo(sb2) + sb);
    float gf1 = ga*(ag1 + cg) + (1.f - ga)*(bfhi(sg2) + sg);
    float bf1 = ba*(ab1 + cb) + (1.f - ba)*(bfhi(sb2) + sb);
    float2 ov;
    ov.x = (xv.x - mn)*rs*(1.f + gf0) + bf0;
    ov.y = (xv.y - mn)*rs*(1.f + gf1) + bf1;
    *(float2*)(op + p) = ov;
  }
}

extern "C" void kernel_launch(void* const* d_in, const int* in_sizes, int n_in,
                              void* d_out, int out_size, void* d_ws, size_t ws_size,
                              hipStream_t stream){
  const float* x    = (const float*)d_in[0];
  const float* seg  = (const float*)d_in[1];
  const float* sty  = (const float*)d_in[2];
  const float* fcw  = (const float*)d_in[3];
  const float* fcb  = (const float*)d_in[4];
  const float* cgw  = (const float*)d_in[5];
  const float* cgb  = (const float*)d_in[6];
  const float* cbw  = (const float*)d_in[7];
  const float* cbb  = (const float*)d_in[8];
  const float* ssw  = (const float*)d_in[9];
  const float* ssb  = (const float*)d_in[10];
  const float* sgw  = (const float*)d_in[11];
  const float* sgb  = (const float*)d_in[12];
  const float* sbw  = (const float*)d_in[13];
  const float* sbb  = (const float*)d_in[14];
  const float* bgam = (const float*)d_in[15];
  const float* bbet = (const float*)d_in[16];
  float* out = (float*)d_out;

  char* ws = (char*)d_ws;
  size_t o = 0;
  auto alloc = [&](size_t n){ size_t r = o; o = (o + n + 255) & ~(size_t)255; return r; };
  float* mean          = (float*)(ws + alloc(512*4));
  float* rstd          = (float*)(ws + alloc(512*4));
  int*   ids           = (int*)  (ws + alloc((size_t)NCELL*4));
  float* mu            = (float*)(ws + alloc((size_t)BB*LL*SS*4));
  float2* G            = (float2*)(ws + alloc((size_t)BB*CC*500*8));
  unsigned short* Tt   = (unsigned short*)(ws + alloc((size_t)20*25*SS*2));
  unsigned short* W2   = (unsigned short*)(ws + alloc((size_t)256*12800*2));
  unsigned short* actv = (unsigned short*)(ws + alloc((size_t)NCELL*SS*2));
  unsigned short* spade= (unsigned short*)(ws + alloc((size_t)BB*256*NPIX*2 < (size_t)2*128*25*512*4
                                                      ? (size_t)2*128*25*512*4
                                                      : (size_t)BB*256*NPIX*2));
  // Wt tables alias spade region (consumed by k_gtab before k_conv writes it)
  float* Wtg = (float*)spade;
  float* Wtb = (float*)spade + (size_t)128*25*512;
  (void)o; (void)ws_size; (void)in_sizes; (void)n_in; (void)out_size; (void)sty;

  k_pre  <<<dim3(21061),dim3(256), 0, stream>>>(x, mean, rstd, seg, ids,
                                                sty, fcw, fcb, mu,
                                                cgw, cbw, Wtg, Wtb,
                                                ssw, Tt, sgw, sbw, W2);
  k_gtab <<<dim3(512),  dim3(256), 0, stream>>>(mu, Wtg, Wtb, G);
  k_actv <<<dim3(2180), dim3(256), 0, stream>>>(ids, Tt, ssb, (int4*)actv);
  k_conv <<<dim3(256),  dim3(512), 0, stream>>>(actv, W2, spade);
  k_final<<<dim3(512),  dim3(256), 0, stream>>>(x, ids, G, spade, mean, rstd,
                                                cgb, cbb, sgb, sbb, bgam, bbet, out);
}

// Round 8
// 466.973 us; speedup vs baseline: 1.4526x; 1.3805x over previous
//
#include <hip/hip_runtime.h>
#include <stdint.h>

#define BB 4
#define CC 128
#define HH 128
#define WW 128
#define LL 19
#define SS 512
#define HP 132
#define NPIX (HH*WW)      // 16384
#define PCELLS (HP*HP)    // 17424
#define NCELL (BB*PCELLS) // 69696

#define SA 192.0f
#define SW 1024.0f
#define INVQ (1.0f/(SA*SW))

typedef float f32x4 __attribute__((ext_vector_type(4)));
typedef int   i32x4 __attribute__((ext_vector_type(4)));

#define AS1Q __attribute__((address_space(1)))
#define AS3Q __attribute__((address_space(3)))
#define MEMFENCE asm volatile("" ::: "memory")

__device__ __forceinline__ void gld16(const void* g, void* l){
  __builtin_amdgcn_global_load_lds((const AS1Q void*)g, (AS3Q void*)l, 16, 0, 0);
}

__device__ inline unsigned short f2bf(float v){
  unsigned u = __float_as_uint(v);
  return (unsigned short)((u + 0x7fffu + ((u >> 16) & 1u)) >> 16);
}
__device__ inline float bflo(unsigned u){ return __uint_as_float(u << 16); }
__device__ inline float bfhi(unsigned u){ return __uint_as_float(u & 0xffff0000u); }

// ------- fused pre-pass: stats(512) | ids(273) | fc(76) | w2t(6400) |
//                         ttab(1000) | w2-int8(3200)  => 11461 blocks ------
__global__ void k_pre(const float* __restrict__ x, float* __restrict__ mean,
                      float* __restrict__ rstd,
                      const float* __restrict__ seg, int* __restrict__ ids,
                      const float* __restrict__ style, const float* __restrict__ fcw,
                      const float* __restrict__ fcb, float* __restrict__ mu,
                      const float* __restrict__ cgw, const float* __restrict__ cbw,
                      float* __restrict__ Wtg, float* __restrict__ Wtb,
                      const float* __restrict__ ssw, unsigned short* __restrict__ Tt,
                      const float* __restrict__ sgw, const float* __restrict__ sbw,
                      unsigned* __restrict__ W2q){
  __shared__ float shmem[4*SS];
  const int blk = blockIdx.x;
  const int t = threadIdx.x;
  if (blk < 512){
    const int bc = blk;
    const int w = t >> 6, lane = t & 63;
    const float4* xv = (const float4*)(x + (size_t)bc * NPIX);
    float s = 0.f, q = 0.f;
    for (int i = t; i < NPIX/4; i += 256){
      float4 v = xv[i];
      s += v.x + v.y + v.z + v.w;
      q += v.x*v.x + v.y*v.y + v.z*v.z + v.w*v.w;
    }
    #pragma unroll
    for (int off = 32; off; off >>= 1){ s += __shfl_down(s, off); q += __shfl_down(q, off); }
    if (lane == 0){ shmem[w] = s; shmem[4 + w] = q; }
    __syncthreads();
    if (t == 0){
      float S = shmem[0]+shmem[1]+shmem[2]+shmem[3];
      float Q = shmem[4]+shmem[5]+shmem[6]+shmem[7];
      float mn = S * (1.f/16384.f);
      float var = Q * (1.f/16384.f) - mn*mn;
      mean[bc] = mn;
      rstd[bc] = rsqrtf(var + 1e-5f);
    }
  } else if (blk < 785){
    int idx = (blk - 512)*256 + t;
    if (idx >= NCELL) return;
    int b = idx / PCELLS; int rem = idx - b*PCELLS;
    int r = rem / HP;     int cp = rem - r*HP;
    int id = LL;
    if (r >= 2 && r <= 129 && cp >= 2 && cp <= 129){
      int p = (r-2)*WW + (cp-2);
      const float* sp = seg + (size_t)b*LL*NPIX + p;
      id = 0;
      for (int j = 0; j < LL; ++j){
        if (sp[(size_t)j*NPIX] > 0.5f){ id = j; break; }
      }
    }
    ids[idx] = id;
  } else if (blk < 861){
    const int jb = blk - 785;
    const int j = jb >> 2, part = jb & 3;
    const int w = t >> 6, lane = t & 63;
    float (*s_s)[SS] = (float(*)[SS])shmem;
    for (int i = t; i < 4*SS; i += 256){
      int b = i >> 9, e = i & 511;
      s_s[b][e] = style[(size_t)(b*LL + j)*SS + e];
    }
    __syncthreads();
    for (int e = part*128 + w; e < part*128 + 128; e += 4){
      const float* row = fcw + ((size_t)(j*SS + e))*SS;
      float a0=0.f, a1=0.f, a2=0.f, a3=0.f;
      #pragma unroll
      for (int i = 0; i < 8; ++i){
        int d = lane + i*64; float rv = row[d];
        a0 += s_s[0][d]*rv; a1 += s_s[1][d]*rv;
        a2 += s_s[2][d]*rv; a3 += s_s[3][d]*rv;
      }
      #pragma unroll
      for (int off = 32; off; off >>= 1){
        a0 += __shfl_down(a0,off); a1 += __shfl_down(a1,off);
        a2 += __shfl_down(a2,off); a3 += __shfl_down(a3,off);
      }
      if (lane == 0){
        float fb = fcb[j*SS + e];
        mu[(size_t)(0*LL+j)*SS + e] = fmaxf(a0+fb, 0.f);
        mu[(size_t)(1*LL+j)*SS + e] = fmaxf(a1+fb, 0.f);
        mu[(size_t)(2*LL+j)*SS + e] = fmaxf(a2+fb, 0.f);
        mu[(size_t)(3*LL+j)*SS + e] = fmaxf(a3+fb, 0.f);
      }
    }
  } else {
    int pb = blk - 861;
    if (pb < 6400){
      int idx = pb*256 + t;                      // 128*25*512
      int e = idx & 511; int rest = idx >> 9;
      int c = rest / 25, d = rest - (rest/25)*25;
      size_t src = ((size_t)c*SS + e)*25 + d;
      Wtg[idx] = cgw[src];
      Wtb[idx] = cbw[src];
    } else if (pb < 7400){
      int idx = (pb-6400)*256 + t;               // 20*25*512
      if (idx < 20*25*SS){
        int s = idx & 511; int rest = idx >> 9;
        int j = rest / 25, d = rest - (rest/25)*25;
        float v = 0.f;
        if (j < LL) v = ssw[((size_t)s*LL + j)*25 + d];
        Tt[idx] = f2bf(v);
      }
    } else {
      // int8 W2: [cpr][12800] bytes, k = tt*64 + kin, tt = schunk*25 + tap,
      // channel s = schunk*64 + kin. 4 bytes per thread.
      int idx4 = (pb-7400)*256 + t;              // 0 .. 819199
      int cpr = idx4 / 3200;
      int r4 = (idx4 - cpr*3200) * 4;            // byte offset in row
      int tt = r4 >> 6; int k0 = r4 & 63;
      int schunk = tt / 25, tap = tt - schunk*25;
      const float* w = (cpr < 128) ? sgw : sbw;
      int c = cpr & 127;
      unsigned pack = 0;
      #pragma unroll
      for (int i = 0; i < 4; ++i){
        int s = schunk*64 + k0 + i;
        float f = w[((size_t)c*SS + s)*25 + tap] * SW;
        int q = (int)rintf(f);
        q = q > 127 ? 127 : (q < -127 ? -127 : q);
        pack |= ((unsigned)(q & 0xFF)) << (8*i);
      }
      W2q[(size_t)cpr*3200 + (idx4 - cpr*3200)] = pack;
    }
  }
}

// ---------------- G table: wave-per-output coalesced dot ------------------
__global__ void k_gtab(const float* __restrict__ mu, const float* __restrict__ Wtg,
                       const float* __restrict__ Wtb, float2* __restrict__ G){
  const int blk = blockIdx.x;
  const int b = blk >> 7, c = blk & 127;
  const int t = threadIdx.x, w = t >> 6, lane = t & 63;
  __shared__ float mu_s[LL*SS];
  for (int i = t; i < LL*SS; i += 256) mu_s[i] = mu[(size_t)b*LL*SS + i];
  __syncthreads();
  for (int i = 0; i < 125; ++i){
    int o = i*4 + w;
    int j = o / 25, d = o - (o/25)*25;
    float ag = 0.f, ab = 0.f;
    if (j < LL){
      const float4* wg4 = (const float4*)(Wtg + ((size_t)c*25 + d)*SS);
      const float4* wb4 = (const float4*)(Wtb + ((size_t)c*25 + d)*SS);
      const float4* m4p = (const float4*)(mu_s + j*SS);
      #pragma unroll
      for (int rp = 0; rp < 2; ++rp){
        int e4 = rp*64 + lane;
        float4 m4 = m4p[e4];
        float4 wv = wg4[e4];
        ag += m4.x*wv.x + m4.y*wv.y + m4.z*wv.z + m4.w*wv.w;
        float4 wv2 = wb4[e4];
        ab += m4.x*wv2.x + m4.y*wv2.y + m4.z*wv2.z + m4.w*wv2.w;
      }
      #pragma unroll
      for (int off = 32; off; off >>= 1){ ag += __shfl_down(ag, off); ab += __shfl_down(ab, off); }
    }
    if (lane == 0) G[((size_t)(b*CC + c))*500 + o] = make_float2(ag, ab);
  }
}

// ------ actv int8: Tt slice in LDS; quantize a*SA, pack 8 bytes/lane ------
__global__ __launch_bounds__(256) void k_actv(
    const int* __restrict__ ids, const unsigned short* __restrict__ Tt,
    const float* __restrict__ ssb, uint2* __restrict__ actv8){
  __shared__ unsigned short Tl[500*136];       // 136000 B
  const int t = threadIdx.x, w = t >> 6, lane = t & 63;
  const int cs  = blockIdx.x & 3;              // channel slice (128 ch)
  const int cg0 = blockIdx.x >> 2;             // cell group (128 cells)
  for (int i = t; i < 8000; i += 256){         // 500 rows x 16 int4
    int row = i >> 4, sub = i & 15;
    int4 v = *(const int4*)(Tt + (size_t)row*512 + cs*128 + sub*8);
    *(int4*)(Tl + row*136 + sub*8) = v;
  }
  __syncthreads();
  const int chsub = lane & 15;
  const int csub  = lane >> 4;
  float bias[8];
  #pragma unroll
  for (int i = 0; i < 8; ++i) bias[i] = ssb[cs*128 + chsub*8 + i];
  for (int it = 0; it < 8; ++it){
    int cell = cg0*128 + it*16 + w*4 + csub;
    if (cell >= NCELL) break;
    int b = cell / PCELLS; int rem = cell - b*PCELLS;
    int r = rem / HP;      int cp = rem - r*HP;
    uint2 outv = {0u, 0u};
    if (r >= 2 && r <= 129 && cp >= 2 && cp <= 129){
      float a[8];
      #pragma unroll
      for (int i = 0; i < 8; ++i) a[i] = bias[i];
      const int* idb = ids + b*PCELLS + (r-2)*HP + (cp-2);
      int idw[25];
      #pragma unroll
      for (int dy = 0; dy < 5; ++dy)
        #pragma unroll
        for (int dx = 0; dx < 5; ++dx) idw[dy*5+dx] = idb[dy*HP + dx];
      #pragma unroll
      for (int tap = 0; tap < 25; ++tap){
        int4 u = *(const int4*)(Tl + (idw[tap]*25 + tap)*136 + chsub*8);
        a[0] += bflo(u.x); a[1] += bfhi(u.x);
        a[2] += bflo(u.y); a[3] += bfhi(u.y);
        a[4] += bflo(u.z); a[5] += bfhi(u.z);
        a[6] += bflo(u.w); a[7] += bfhi(u.w);
      }
      unsigned q[8];
      #pragma unroll
      for (int i = 0; i < 8; ++i){
        int v = (int)(fmaxf(a[i], 0.f)*SA + 0.5f);
        q[i] = (unsigned)(v > 127 ? 127 : v);
      }
      outv.x = q[0] | (q[1]<<8) | (q[2]<<16) | (q[3]<<24);
      outv.y = q[4] | (q[5]<<8) | (q[6]<<16) | (q[7]<<24);
    }
    actv8[(size_t)cell*64 + cs*16 + chsub] = outv;
  }
}

// ------- big conv int8: BK=64, 200 steps, 1 barrier/step, ping-pong -------
__global__ __launch_bounds__(512, 2) void k_conv(
    const unsigned char* __restrict__ actv8,   // i8 [B][132][132][512]
    const unsigned char* __restrict__ W2q,     // i8 [256][12800] (tt-major)
    unsigned short* __restrict__ spade)        // bf16 [B][256][128][128]
{
  __shared__ int4 lds4[131072/16];             // 128 KiB: 4 bufs x (A 16K + B 16K)
  char* ldsb = (char*)lds4;
  const int blk = blockIdx.x;
  const int b  = blk >> 6;
  const int y0 = (blk & 63) * 2;
  const int t  = threadIdx.x;
  const int lane = t & 63;
  const int w  = t >> 6;
  const int wr = w >> 2, wc = w & 3;
  const int li = lane & 15, q = lane >> 4;

  // staging: source pre-swizzle (geometry identical to verified bf16 R1-R6;
  // 64B rows, 4 x 16B slots; slot now = 16 channels of i8)
  const int lsub  = lane >> 2;
  const int s_src = (lane & 3) ^ ((lane >> 3) & 3);
  const bool isA  = (w < 4);
  const char* p0[4];
  int ldsrel[4];
  #pragma unroll
  for (int l = 0; l < 4; ++l){
    int row = (isA ? w : (w - 4)) * 64 + l*16 + lsub;
    if (isA){
      int y = y0 + (row >> 7), x = row & 127;
      p0[l] = (const char*)(actv8 + (((size_t)b*HP + y)*HP + x)*SS + s_src*16);
    } else {
      p0[l] = (const char*)(W2q + (size_t)row*12800 + s_src*16);
    }
    ldsrel[l] = w*4096 + l*1024 + lane*16;
  }

  auto stage_tt = [&](int tt){               // 4 x 16B loads/thread
    int schunk = tt / 25; int tap = tt - schunk*25;
    int dy = tap / 5, dx = tap - dy*5;
    size_t offA = (size_t)(dy*HP + dx)*SS + (size_t)schunk*64;
    size_t off = isA ? offA : (size_t)tt * 64;
    char* base = ldsb + ((tt & 3) * 32768);
    #pragma unroll
    for (int l = 0; l < 4; ++l)
      gld16(p0[l] + off, base + ldsrel[l]);
  };

  i32x4 acc[8][4];
  #pragma unroll
  for (int m = 0; m < 8; ++m)
    #pragma unroll
    for (int n = 0; n < 4; ++n) acc[m][n] = (i32x4){0,0,0,0};

  const int swz  = (q ^ ((li >> 1) & 3)) * 16;
  const int arel = (wr*128 + li)*64 + swz;
  const int brel = 16384 + (wc*64 + li)*64 + swz;

  i32x4 a03[2][4], bv[2][4], a47[4];

  // prologue: 3 tiles in flight; preload tile-0 low fragments
  stage_tt(0); stage_tt(1); stage_tt(2);
  asm volatile("s_waitcnt vmcnt(8)" ::: "memory");   // tile 0 landed
  __builtin_amdgcn_s_barrier();
  MEMFENCE;
  #pragma unroll
  for (int m = 0; m < 4; ++m) a03[0][m] = *(const i32x4*)(ldsb + arel + m*1024);
  #pragma unroll
  for (int n = 0; n < 4; ++n) bv[0][n]  = *(const i32x4*)(ldsb + brel + n*1024);

  // main: T = 0..197, single barrier per step, counted vmcnt(4)
  for (int T2 = 0; T2 < 99; ++T2){
    #pragma unroll
    for (int half = 0; half < 2; ++half){
      const int T = 2*T2 + half;
      const char* buf  = ldsb + ((unsigned)T & 3u)*32768;
      const char* bufn = ldsb + ((unsigned)(T+1) & 3u)*32768;
      const int cur = half, nxt = half ^ 1;
      #pragma unroll
      for (int m = 0; m < 4; ++m) a47[m] = *(const i32x4*)(buf + arel + (m+4)*1024);
      MEMFENCE;
      asm volatile("s_waitcnt vmcnt(4)" ::: "memory");
      __builtin_amdgcn_s_barrier();
      MEMFENCE;
      if (T <= 196) stage_tt(T + 3);
      MEMFENCE;
      __builtin_amdgcn_s_setprio(1);
      #pragma unroll
      for (int m = 0; m < 4; ++m)
        #pragma unroll
        for (int n = 0; n < 4; ++n)
          acc[m][n] = __builtin_amdgcn_mfma_i32_16x16x64_i8(a03[cur][m], bv[cur][n], acc[m][n], 0, 0, 0);
      __builtin_amdgcn_s_setprio(0);
      MEMFENCE;
      #pragma unroll
      for (int m = 0; m < 4; ++m) a03[nxt][m] = *(const i32x4*)(bufn + arel + m*1024);
      #pragma unroll
      for (int n = 0; n < 4; ++n) bv[nxt][n]  = *(const i32x4*)(bufn + brel + n*1024);
      MEMFENCE;
      __builtin_amdgcn_s_setprio(1);
      #pragma unroll
      for (int m = 0; m < 4; ++m)
        #pragma unroll
        for (int n = 0; n < 4; ++n)
          acc[m+4][n] = __builtin_amdgcn_mfma_i32_16x16x64_i8(a47[m], bv[cur][n], acc[m+4][n], 0, 0, 0);
      __builtin_amdgcn_s_setprio(0);
      MEMFENCE;
    }
  }
  // T = 198 (set 0 holds tile 198)
  {
    const char* buf  = ldsb + (198 & 3)*32768;
    const char* bufn = ldsb + (199 & 3)*32768;
    #pragma unroll
    for (int m = 0; m < 4; ++m) a47[m] = *(const i32x4*)(buf + arel + (m+4)*1024);
    MEMFENCE;
    asm volatile("s_waitcnt vmcnt(0)" ::: "memory");
    __builtin_amdgcn_s_barrier();
    MEMFENCE;
    #pragma unroll
    for (int m = 0; m < 4; ++m)
      #pragma unroll
      for (int n = 0; n < 4; ++n)
        acc[m][n] = __builtin_amdgcn_mfma_i32_16x16x64_i8(a03[0][m], bv[0][n], acc[m][n], 0, 0, 0);
    #pragma unroll
    for (int m = 0; m < 4; ++m) a03[1][m] = *(const i32x4*)(bufn + arel + m*1024);
    #pragma unroll
    for (int n = 0; n < 4; ++n) bv[1][n]  = *(const i32x4*)(bufn + brel + n*1024);
    #pragma unroll
    for (int m = 0; m < 4; ++m)
      #pragma unroll
      for (int n = 0; n < 4; ++n)
        acc[m+4][n] = __builtin_amdgcn_mfma_i32_16x16x64_i8(a47[m], bv[0][n], acc[m+4][n], 0, 0, 0);
  }
  // T = 199 (set 1 holds tile 199)
  {
    const char* buf = ldsb + (199 & 3)*32768;
    #pragma unroll
    for (int m = 0; m < 4; ++m) a47[m] = *(const i32x4*)(buf + arel + (m+4)*1024);
    #pragma unroll
    for (int m = 0; m < 4; ++m)
      #pragma unroll
      for (int n = 0; n < 4; ++n)
        acc[m][n] = __builtin_amdgcn_mfma_i32_16x16x64_i8(a03[1][m], bv[1][n], acc[m][n], 0, 0, 0);
    #pragma unroll
    for (int m = 0; m < 4; ++m)
      #pragma unroll
      for (int n = 0; n < 4; ++n)
        acc[m+4][n] = __builtin_amdgcn_mfma_i32_16x16x64_i8(a47[m], bv[1][n], acc[m+4][n], 0, 0, 0);
  }

  // epilogue: dequant i32 -> f32, pack bf16; D col=lane&15 -> c', row -> px
  const int xq4 = (lane >> 4) << 2;
  const int cq  = wc*64 + (lane & 15);
  #pragma unroll
  for (int m = 0; m < 8; ++m){
    int p = wr*128 + m*16 + xq4;
    int y = y0 + (p >> 7), x = p & 127;
    #pragma unroll
    for (int n = 0; n < 4; ++n){
      int cp = cq + n*16;
      i32x4 a = acc[m][n];
      uint2 pk;
      pk.x = (unsigned)f2bf((float)a.x * INVQ) | ((unsigned)f2bf((float)a.y * INVQ) << 16);
      pk.y = (unsigned)f2bf((float)a.z * INVQ) | ((unsigned)f2bf((float)a.w * INVQ) << 16);
      *(uint2*)(spade + (((size_t)(b*256 + cp))*HH + y)*WW + x) = pk;
    }
  }
}

// ---------------- final: paired-pixel gather + blend + IN apply -----------
__global__ void k_final(const float* __restrict__ xin, const int* __restrict__ ids,
                        const float2* __restrict__ G, const unsigned short* __restrict__ spade,
                        const float* __restrict__ mean, const float* __restrict__ rstd,
                        const float* __restrict__ cgb, const float* __restrict__ cbb,
                        const float* __restrict__ sgb, const float* __restrict__ sbb,
                        const float* __restrict__ bgam, const float* __restrict__ bbet,
                        float* __restrict__ out){
  const int blk = blockIdx.x;
  const int b = blk >> 7, c = blk & 127;
  const int t = threadIdx.x;
  __shared__ float2 Gl2[500];                  // [tap][id] transposed
  for (int i = t; i < 500; i += 256){
    int j = i / 25, d = i - (i/25)*25;
    Gl2[d*20 + j] = G[((size_t)(b*CC + c))*500 + i];
  }
  __syncthreads();
  const float ga = 1.f/(1.f + __expf(-bgam[0]));
  const float ba = 1.f/(1.f + __expf(-bbet[0]));
  const float mn = mean[b*CC + c], rs = rstd[b*CC + c];
  const float cg = cgb[c], cb = cbb[c], sg = sgb[c], sb = sbb[c];
  const float* xp  = xin + (size_t)(b*CC + c)*NPIX;
  const unsigned short* spg = spade + (size_t)(b*256 + c)*NPIX;
  const unsigned short* spb = spade + (size_t)(b*256 + c + 128)*NPIX;
  float* op = out + (size_t)(b*CC + c)*NPIX;
  const int* idb = ids + b*PCELLS;
  for (int p2 = t; p2 < NPIX/2; p2 += 256){
    int p = p2*2;
    int y = p >> 7, x = p & 127;
    float ag0=0.f, ab0=0.f, ag1=0.f, ab1=0.f;
    #pragma unroll
    for (int dy = 0; dy < 5; ++dy){
      const int* row = idb + (y+dy)*HP + x;
      int idv[6];
      #pragma unroll
      for (int k = 0; k < 6; ++k) idv[k] = row[k];
      #pragma unroll
      for (int dx = 0; dx < 5; ++dx){
        float2 g0 = Gl2[(dy*5+dx)*20 + idv[dx]];
        float2 g1 = Gl2[(dy*5+dx)*20 + idv[dx+1]];
        ag0 += g0.x; ab0 += g0.y;
        ag1 += g1.x; ab1 += g1.y;
      }
    }
    unsigned sg2 = *(const unsigned*)(spg + p);
    unsigned sb2 = *(const unsigned*)(spb + p);
    float2 xv = *(const float2*)(xp + p);
    float gf0 = ga*(ag0 + cg) + (1.f - ga)*(bflo(sg2) + sg);
    float bf0 = ba*(ab0 + cb) + (1.f - ba)*(bflo(sb2) + sb);
    float gf1 = ga*(ag1 + cg) + (1.f - ga)*(bfhi(sg2) + sg);
    float bf1 = ba*(ab1 + cb) + (1.f - ba)*(bfhi(sb2) + sb);
    float2 ov;
    ov.x = (xv.x - mn)*rs*(1.f + gf0) + bf0;
    ov.y = (xv.y - mn)*rs*(1.f + gf1) + bf1;
    *(float2*)(op + p) = ov;
  }
}

extern "C" void kernel_launch(void* const* d_in, const int* in_sizes, int n_in,
                              void* d_out, int out_size, void* d_ws, size_t ws_size,
                              hipStream_t stream){
  const float* x    = (const float*)d_in[0];
  const float* seg  = (const float*)d_in[1];
  const float* sty  = (const float*)d_in[2];
  const float* fcw  = (const float*)d_in[3];
  const float* fcb  = (const float*)d_in[4];
  const float* cgw  = (const float*)d_in[5];
  const float* cgb  = (const float*)d_in[6];
  const float* cbw  = (const float*)d_in[7];
  const float* cbb  = (const float*)d_in[8];
  const float* ssw  = (const float*)d_in[9];
  const float* ssb  = (const float*)d_in[10];
  const float* sgw  = (const float*)d_in[11];
  const float* sgb  = (const float*)d_in[12];
  const float* sbw  = (const float*)d_in[13];
  const float* sbb  = (const float*)d_in[14];
  const float* bgam = (const float*)d_in[15];
  const float* bbet = (const float*)d_in[16];
  float* out = (float*)d_out;

  char* ws = (char*)d_ws;
  size_t o = 0;
  auto alloc = [&](size_t n){ size_t r = o; o = (o + n + 255) & ~(size_t)255; return r; };
  float* mean          = (float*)(ws + alloc(512*4));
  float* rstd          = (float*)(ws + alloc(512*4));
  int*   ids           = (int*)  (ws + alloc((size_t)NCELL*4));
  float* mu            = (float*)(ws + alloc((size_t)BB*LL*SS*4));
  float2* G            = (float2*)(ws + alloc((size_t)BB*CC*500*8));
  unsigned short* Tt   = (unsigned short*)(ws + alloc((size_t)20*25*SS*2));
  unsigned char* W2q   = (unsigned char*)(ws + alloc((size_t)256*12800));
  unsigned char* actv8 = (unsigned char*)(ws + alloc((size_t)NCELL*SS));
  unsigned short* spade= (unsigned short*)(ws + alloc((size_t)BB*256*NPIX*2 < (size_t)2*128*25*512*4
                                                      ? (size_t)2*128*25*512*4
                                                      : (size_t)BB*256*NPIX*2));
  // Wt tables alias spade region (consumed by k_gtab before k_conv writes it)
  float* Wtg = (float*)spade;
  float* Wtb = (float*)spade + (size_t)128*25*512;
  (void)o; (void)ws_size; (void)in_sizes; (void)n_in; (void)out_size; (void)sty;

  k_pre  <<<dim3(11461),dim3(256), 0, stream>>>(x, mean, rstd, seg, ids,
                                                sty, fcw, fcb, mu,
                                                cgw, cbw, Wtg, Wtb,
                                                ssw, Tt, sgw, sbw, (unsigned*)W2q);
  k_gtab <<<dim3(512),  dim3(256), 0, stream>>>(mu, Wtg, Wtb, G);
  k_actv <<<dim3(2180), dim3(256), 0, stream>>>(ids, Tt, ssb, (uint2*)actv8);
  k_conv <<<dim3(256),  dim3(512), 0, stream>>>(actv8, W2q, spade);
  k_final<<<dim3(512),  dim3(256), 0, stream>>>(x, ids, G, spade, mean, rstd,
                                                cgb, cbb, sgb, sbb, bgam, bbet, out);
}

// Round 9
// 403.088 us; speedup vs baseline: 1.6828x; 1.1585x over previous
//
#include <hip/hip_runtime.h>
#include <stdint.h>

#define BB 4
#define CC 128
#define HH 128
#define WW 128
#define LL 19
#define SS 512
#define HP 132
#define NPIX (HH*WW)      // 16384
#define PCELLS (HP*HP)    // 17424
#define NCELL (BB*PCELLS) // 69696

#define SA 192.0f
#define SW 1024.0f
#define INVQ (1.0f/(SA*SW))

typedef float f32x4 __attribute__((ext_vector_type(4)));
typedef int   i32x4 __attribute__((ext_vector_type(4)));

#define AS1Q __attribute__((address_space(1)))
#define AS3Q __attribute__((address_space(3)))
#define MEMFENCE asm volatile("" ::: "memory")

__device__ __forceinline__ void gld16(const void* g, void* l){
  __builtin_amdgcn_global_load_lds((const AS1Q void*)g, (AS3Q void*)l, 16, 0, 0);
}

__device__ inline unsigned short f2bf(float v){
  unsigned u = __float_as_uint(v);
  return (unsigned short)((u + 0x7fffu + ((u >> 16) & 1u)) >> 16);
}
__device__ inline float bflo(unsigned u){ return __uint_as_float(u << 16); }
__device__ inline float bfhi(unsigned u){ return __uint_as_float(u & 0xffff0000u); }

// ------- fused pre-pass -----------------------------------------------
// blocks: [0,512) stats | [512,785) ids | [785,861) fc |
//         [861,1117) w2t LDS-transpose | [1117,2117) ttab |
//         [2117,2373) w2q int8 LDS-transpose
__global__ __launch_bounds__(256) void k_pre(
                      const float* __restrict__ x, float* __restrict__ mean,
                      float* __restrict__ rstd,
                      const float* __restrict__ seg, int* __restrict__ ids,
                      const float* __restrict__ style, const float* __restrict__ fcw,
                      const float* __restrict__ fcb, float* __restrict__ mu,
                      const float* __restrict__ cgw, const float* __restrict__ cbw,
                      float* __restrict__ Wtg, float* __restrict__ Wtb,
                      const float* __restrict__ ssw, unsigned short* __restrict__ Tt,
                      const float* __restrict__ sgw, const float* __restrict__ sbw,
                      unsigned* __restrict__ W2q){
  __shared__ float shmem[12800];               // 51.2 KB
  const int blk = blockIdx.x;
  const int t = threadIdx.x;
  if (blk < 512){
    const int bc = blk;
    const int w = t >> 6, lane = t & 63;
    const float4* xv = (const float4*)(x + (size_t)bc * NPIX);
    float s = 0.f, q = 0.f;
    for (int i = t; i < NPIX/4; i += 256){
      float4 v = xv[i];
      s += v.x + v.y + v.z + v.w;
      q += v.x*v.x + v.y*v.y + v.z*v.z + v.w*v.w;
    }
    #pragma unroll
    for (int off = 32; off; off >>= 1){ s += __shfl_down(s, off); q += __shfl_down(q, off); }
    if (lane == 0){ shmem[w] = s; shmem[4 + w] = q; }
    __syncthreads();
    if (t == 0){
      float S = shmem[0]+shmem[1]+shmem[2]+shmem[3];
      float Q = shmem[4]+shmem[5]+shmem[6]+shmem[7];
      float mn = S * (1.f/16384.f);
      float var = Q * (1.f/16384.f) - mn*mn;
      mean[bc] = mn;
      rstd[bc] = rsqrtf(var + 1e-5f);
    }
  } else if (blk < 785){
    int idx = (blk - 512)*256 + t;
    if (idx >= NCELL) return;
    int b = idx / PCELLS; int rem = idx - b*PCELLS;
    int r = rem / HP;     int cp = rem - r*HP;
    int id = LL;
    if (r >= 2 && r <= 129 && cp >= 2 && cp <= 129){
      int p = (r-2)*WW + (cp-2);
      const float* sp = seg + (size_t)b*LL*NPIX + p;
      id = 0;
      for (int j = 0; j < LL; ++j){
        if (sp[(size_t)j*NPIX] > 0.5f){ id = j; break; }
      }
    }
    ids[idx] = id;
  } else if (blk < 861){
    const int jb = blk - 785;
    const int j = jb >> 2, part = jb & 3;
    const int w = t >> 6, lane = t & 63;
    float (*s_s)[SS] = (float(*)[SS])shmem;
    for (int i = t; i < 4*SS; i += 256){
      int b = i >> 9, e = i & 511;
      s_s[b][e] = style[(size_t)(b*LL + j)*SS + e];
    }
    __syncthreads();
    for (int e = part*128 + w; e < part*128 + 128; e += 4){
      const float* row = fcw + ((size_t)(j*SS + e))*SS;
      float a0=0.f, a1=0.f, a2=0.f, a3=0.f;
      #pragma unroll
      for (int i = 0; i < 8; ++i){
        int d = lane + i*64; float rv = row[d];
        a0 += s_s[0][d]*rv; a1 += s_s[1][d]*rv;
        a2 += s_s[2][d]*rv; a3 += s_s[3][d]*rv;
      }
      #pragma unroll
      for (int off = 32; off; off >>= 1){
        a0 += __shfl_down(a0,off); a1 += __shfl_down(a1,off);
        a2 += __shfl_down(a2,off); a3 += __shfl_down(a3,off);
      }
      if (lane == 0){
        float fb = fcb[j*SS + e];
        mu[(size_t)(0*LL+j)*SS + e] = fmaxf(a0+fb, 0.f);
        mu[(size_t)(1*LL+j)*SS + e] = fmaxf(a1+fb, 0.f);
        mu[(size_t)(2*LL+j)*SS + e] = fmaxf(a2+fb, 0.f);
        mu[(size_t)(3*LL+j)*SS + e] = fmaxf(a3+fb, 0.f);
      }
    }
  } else if (blk < 1117){
    // ---- w2t: coalesced read -> LDS -> coalesced transposed write ----
    int pb = blk - 861;                        // 0..255
    int c = pb >> 1;
    const float* src = ((pb & 1) ? cbw : cgw) + (size_t)c*12800;  // [e][d]
    float* dst = ((pb & 1) ? Wtb : Wtg) + (size_t)c*12800;        // [d][e]
    for (int i = t; i < 12800; i += 256) shmem[i] = src[i];
    __syncthreads();
    for (int i = t; i < 12800; i += 256){
      int dd = i >> 9, e = i & 511;            // i = dd*512 + e
      dst[i] = shmem[e*25 + dd];               // stride-25 LDS read: conflict-free
    }
  } else if (blk < 2117){
    int idx = (blk-1117)*256 + t;              // 20*25*512
    int s = idx & 511; int rest = idx >> 9;
    int j = rest / 25, d = rest - (rest/25)*25;
    float v = 0.f;
    if (j < LL) v = ssw[((size_t)s*LL + j)*25 + d];
    Tt[idx] = f2bf(v);
  } else {
    // ---- w2q int8: coalesced read -> LDS -> quantized reorder write ----
    int cpr = blk - 2117;                      // 0..255
    const float* w = (cpr < 128) ? sgw : sbw;
    int c = cpr & 127;
    const float* src = w + (size_t)c*12800;    // [e][d]
    for (int i = t; i < 12800; i += 256) shmem[i] = src[i];
    __syncthreads();
    for (int wd = t; wd < 3200; wd += 256){
      int r4 = wd*4; int tt = r4 >> 6; int k0 = r4 & 63;
      int schunk = tt/25, tap = tt - schunk*25;
      unsigned pack = 0;
      #pragma unroll
      for (int i = 0; i < 4; ++i){
        int s = schunk*64 + k0 + i;
        int q = (int)rintf(shmem[s*25 + tap] * SW);
        q = q > 127 ? 127 : (q < -127 ? -127 : q);
        pack |= ((unsigned)(q & 0xFF)) << (8*i);
      }
      W2q[(size_t)cpr*3200 + wd] = pack;
    }
  }
}

// ---------------- G table: wave-per-output coalesced dot ------------------
__global__ void k_gtab(const float* __restrict__ mu, const float* __restrict__ Wtg,
                       const float* __restrict__ Wtb, float2* __restrict__ G){
  const int blk = blockIdx.x;
  const int b = blk >> 7, c = blk & 127;
  const int t = threadIdx.x, w = t >> 6, lane = t & 63;
  __shared__ float mu_s[LL*SS];
  for (int i = t; i < LL*SS; i += 256) mu_s[i] = mu[(size_t)b*LL*SS + i];
  __syncthreads();
  for (int i = 0; i < 125; ++i){
    int o = i*4 + w;
    int j = o / 25, d = o - (o/25)*25;
    float ag = 0.f, ab = 0.f;
    if (j < LL){
      const float4* wg4 = (const float4*)(Wtg + ((size_t)c*25 + d)*SS);
      const float4* wb4 = (const float4*)(Wtb + ((size_t)c*25 + d)*SS);
      const float4* m4p = (const float4*)(mu_s + j*SS);
      #pragma unroll
      for (int rp = 0; rp < 2; ++rp){
        int e4 = rp*64 + lane;
        float4 m4 = m4p[e4];
        float4 wv = wg4[e4];
        ag += m4.x*wv.x + m4.y*wv.y + m4.z*wv.z + m4.w*wv.w;
        float4 wv2 = wb4[e4];
        ab += m4.x*wv2.x + m4.y*wv2.y + m4.z*wv2.z + m4.w*wv2.w;
      }
      #pragma unroll
      for (int off = 32; off; off >>= 1){ ag += __shfl_down(ag, off); ab += __shfl_down(ab, off); }
    }
    if (lane == 0) G[((size_t)(b*CC + c))*500 + o] = make_float2(ag, ab);
  }
}

// ------ actv int8: 512 threads (2 waves/SIMD), Tt slice in LDS ------------
__global__ __launch_bounds__(512) void k_actv(
    const int* __restrict__ ids, const unsigned short* __restrict__ Tt,
    const float* __restrict__ ssb, uint2* __restrict__ actv8){
  __shared__ unsigned short Tl[500*136];       // 136000 B
  const int t = threadIdx.x, w = t >> 6, lane = t & 63;
  const int cs  = blockIdx.x & 3;              // channel slice (128 ch)
  const int cg0 = blockIdx.x >> 2;             // cell group (256 cells)
  for (int i = t; i < 8000; i += 512){         // 500 rows x 16 int4
    int row = i >> 4, sub = i & 15;
    int4 v = *(const int4*)(Tt + (size_t)row*512 + cs*128 + sub*8);
    *(int4*)(Tl + row*136 + sub*8) = v;
  }
  __syncthreads();
  const int chsub = lane & 15;
  const int csub  = lane >> 4;
  float bias[8];
  #pragma unroll
  for (int i = 0; i < 8; ++i) bias[i] = ssb[cs*128 + chsub*8 + i];
  for (int it = 0; it < 8; ++it){
    int cell = cg0*256 + it*32 + w*4 + csub;
    if (cell >= NCELL) break;
    int b = cell / PCELLS; int rem = cell - b*PCELLS;
    int r = rem / HP;      int cp = rem - r*HP;
    uint2 outv = {0u, 0u};
    if (r >= 2 && r <= 129 && cp >= 2 && cp <= 129){
      float a[8];
      #pragma unroll
      for (int i = 0; i < 8; ++i) a[i] = bias[i];
      const int* idb = ids + b*PCELLS + (r-2)*HP + (cp-2);
      int idw[25];
      #pragma unroll
      for (int dy = 0; dy < 5; ++dy)
        #pragma unroll
        for (int dx = 0; dx < 5; ++dx) idw[dy*5+dx] = idb[dy*HP + dx];
      #pragma unroll
      for (int tap = 0; tap < 25; ++tap){
        int4 u = *(const int4*)(Tl + (idw[tap]*25 + tap)*136 + chsub*8);
        a[0] += bflo(u.x); a[1] += bfhi(u.x);
        a[2] += bflo(u.y); a[3] += bfhi(u.y);
        a[4] += bflo(u.z); a[5] += bfhi(u.z);
        a[6] += bflo(u.w); a[7] += bfhi(u.w);
      }
      unsigned q[8];
      #pragma unroll
      for (int i = 0; i < 8; ++i){
        int v = (int)(fmaxf(a[i], 0.f)*SA + 0.5f);
        q[i] = (unsigned)(v > 127 ? 127 : v);
      }
      outv.x = q[0] | (q[1]<<8) | (q[2]<<16) | (q[3]<<24);
      outv.y = q[4] | (q[5]<<8) | (q[6]<<16) | (q[7]<<24);
    }
    actv8[(size_t)cell*64 + cs*16 + chsub] = outv;
  }
}

// ------- big conv int8: BK=64, 200 steps, 1 barrier/step, ping-pong -------
__global__ __launch_bounds__(512, 2) void k_conv(
    const unsigned char* __restrict__ actv8,   // i8 [B][132][132][512]
    const unsigned char* __restrict__ W2q,     // i8 [256][12800] (tt-major)
    unsigned short* __restrict__ spade)        // bf16 [B][256][128][128]
{
  __shared__ int4 lds4[131072/16];             // 128 KiB: 4 bufs x (A 16K + B 16K)
  char* ldsb = (char*)lds4;
  // bijective XCD swizzle (grid 256 = 8 XCD x 32): y-adjacent blocks co-reside
  const int bid = blockIdx.x;
  const int blk = (bid & 7)*32 + (bid >> 3);
  const int b  = blk >> 6;
  const int y0 = (blk & 63) * 2;
  const int t  = threadIdx.x;
  const int lane = t & 63;
  const int w  = t >> 6;
  const int wr = w >> 2, wc = w & 3;
  const int li = lane & 15, q = lane >> 4;

  const int lsub  = lane >> 2;
  const int s_src = (lane & 3) ^ ((lane >> 3) & 3);
  const bool isA  = (w < 4);
  const char* p0[4];
  int ldsrel[4];
  #pragma unroll
  for (int l = 0; l < 4; ++l){
    int row = (isA ? w : (w - 4)) * 64 + l*16 + lsub;
    if (isA){
      int y = y0 + (row >> 7), x = row & 127;
      p0[l] = (const char*)(actv8 + (((size_t)b*HP + y)*HP + x)*SS + s_src*16);
    } else {
      p0[l] = (const char*)(W2q + (size_t)row*12800 + s_src*16);
    }
    ldsrel[l] = w*4096 + l*1024 + lane*16;
  }

  auto stage_tt = [&](int tt){               // 4 x 16B loads/thread
    int schunk = tt / 25; int tap = tt - schunk*25;
    int dy = tap / 5, dx = tap - dy*5;
    size_t offA = (size_t)(dy*HP + dx)*SS + (size_t)schunk*64;
    size_t off = isA ? offA : (size_t)tt * 64;
    char* base = ldsb + ((tt & 3) * 32768);
    #pragma unroll
    for (int l = 0; l < 4; ++l)
      gld16(p0[l] + off, base + ldsrel[l]);
  };

  i32x4 acc[8][4];
  #pragma unroll
  for (int m = 0; m < 8; ++m)
    #pragma unroll
    for (int n = 0; n < 4; ++n) acc[m][n] = (i32x4){0,0,0,0};

  const int swz  = (q ^ ((li >> 1) & 3)) * 16;
  const int arel = (wr*128 + li)*64 + swz;
  const int brel = 16384 + (wc*64 + li)*64 + swz;

  i32x4 a03[2][4], bv[2][4], a47[4];

  stage_tt(0); stage_tt(1); stage_tt(2);
  asm volatile("s_waitcnt vmcnt(8)" ::: "memory");
  __builtin_amdgcn_s_barrier();
  MEMFENCE;
  #pragma unroll
  for (int m = 0; m < 4; ++m) a03[0][m] = *(const i32x4*)(ldsb + arel + m*1024);
  #pragma unroll
  for (int n = 0; n < 4; ++n) bv[0][n]  = *(const i32x4*)(ldsb + brel + n*1024);

  for (int T2 = 0; T2 < 99; ++T2){
    #pragma unroll
    for (int half = 0; half < 2; ++half){
      const int T = 2*T2 + half;
      const char* buf  = ldsb + ((unsigned)T & 3u)*32768;
      const char* bufn = ldsb + ((unsigned)(T+1) & 3u)*32768;
      const int cur = half, nxt = half ^ 1;
      #pragma unroll
      for (int m = 0; m < 4; ++m) a47[m] = *(const i32x4*)(buf + arel + (m+4)*1024);
      MEMFENCE;
      asm volatile("s_waitcnt vmcnt(4)" ::: "memory");
      __builtin_amdgcn_s_barrier();
      MEMFENCE;
      if (T <= 196) stage_tt(T + 3);
      MEMFENCE;
      __builtin_amdgcn_s_setprio(1);
      #pragma unroll
      for (int m = 0; m < 4; ++m)
        #pragma unroll
        for (int n = 0; n < 4; ++n)
          acc[m][n] = __builtin_amdgcn_mfma_i32_16x16x64_i8(a03[cur][m], bv[cur][n], acc[m][n], 0, 0, 0);
      __builtin_amdgcn_s_setprio(0);
      MEMFENCE;
      #pragma unroll
      for (int m = 0; m < 4; ++m) a03[nxt][m] = *(const i32x4*)(bufn + arel + m*1024);
      #pragma unroll
      for (int n = 0; n < 4; ++n) bv[nxt][n]  = *(const i32x4*)(bufn + brel + n*1024);
      MEMFENCE;
      __builtin_amdgcn_s_setprio(1);
      #pragma unroll
      for (int m = 0; m < 4; ++m)
        #pragma unroll
        for (int n = 0; n < 4; ++n)
          acc[m+4][n] = __builtin_amdgcn_mfma_i32_16x16x64_i8(a47[m], bv[cur][n], acc[m+4][n], 0, 0, 0);
      __builtin_amdgcn_s_setprio(0);
      MEMFENCE;
    }
  }
  // T = 198
  {
    const char* buf  = ldsb + (198 & 3)*32768;
    const char* bufn = ldsb + (199 & 3)*32768;
    #pragma unroll
    for (int m = 0; m < 4; ++m) a47[m] = *(const i32x4*)(buf + arel + (m+4)*1024);
    MEMFENCE;
    asm volatile("s_waitcnt vmcnt(0)" ::: "memory");
    __builtin_amdgcn_s_barrier();
    MEMFENCE;
    #pragma unroll
    for (int m = 0; m < 4; ++m)
      #pragma unroll
      for (int n = 0; n < 4; ++n)
        acc[m][n] = __builtin_amdgcn_mfma_i32_16x16x64_i8(a03[0][m], bv[0][n], acc[m][n], 0, 0, 0);
    #pragma unroll
    for (int m = 0; m < 4; ++m) a03[1][m] = *(const i32x4*)(bufn + arel + m*1024);
    #pragma unroll
    for (int n = 0; n < 4; ++n) bv[1][n]  = *(const i32x4*)(bufn + brel + n*1024);
    #pragma unroll
    for (int m = 0; m < 4; ++m)
      #pragma unroll
      for (int n = 0; n < 4; ++n)
        acc[m+4][n] = __builtin_amdgcn_mfma_i32_16x16x64_i8(a47[m], bv[0][n], acc[m+4][n], 0, 0, 0);
  }
  // T = 199
  {
    const char* buf = ldsb + (199 & 3)*32768;
    #pragma unroll
    for (int m = 0; m < 4; ++m) a47[m] = *(const i32x4*)(buf + arel + (m+4)*1024);
    #pragma unroll
    for (int m = 0; m < 4; ++m)
      #pragma unroll
      for (int n = 0; n < 4; ++n)
        acc[m][n] = __builtin_amdgcn_mfma_i32_16x16x64_i8(a03[1][m], bv[1][n], acc[m][n], 0, 0, 0);
    #pragma unroll
    for (int m = 0; m < 4; ++m)
      #pragma unroll
      for (int n = 0; n < 4; ++n)
        acc[m+4][n] = __builtin_amdgcn_mfma_i32_16x16x64_i8(a47[m], bv[1][n], acc[m+4][n], 0, 0, 0);
  }

  // epilogue: dequant i32 -> f32, pack bf16
  const int xq4 = (lane >> 4) << 2;
  const int cq  = wc*64 + (lane & 15);
  #pragma unroll
  for (int m = 0; m < 8; ++m){
    int p = wr*128 + m*16 + xq4;
    int y = y0 + (p >> 7), x = p & 127;
    #pragma unroll
    for (int n = 0; n < 4; ++n){
      int cp = cq + n*16;
      i32x4 a = acc[m][n];
      uint2 pk;
      pk.x = (unsigned)f2bf((float)a.x * INVQ) | ((unsigned)f2bf((float)a.y * INVQ) << 16);
      pk.y = (unsigned)f2bf((float)a.z * INVQ) | ((unsigned)f2bf((float)a.w * INVQ) << 16);
      *(uint2*)(spade + (((size_t)(b*256 + cp))*HH + y)*WW + x) = pk;
    }
  }
}

// ---------------- final: paired-pixel gather + blend + IN apply -----------
__global__ void k_final(const float* __restrict__ xin, const int* __restrict__ ids,
                        const float2* __restrict__ G, const unsigned short* __restrict__ spade,
                        const float* __restrict__ mean, const float* __restrict__ rstd,
                        const float* __restrict__ cgb, const float* __restrict__ cbb,
                        const float* __restrict__ sgb, const float* __restrict__ sbb,
                        const float* __restrict__ bgam, const float* __restrict__ bbet,
                        float* __restrict__ out){
  const int blk = blockIdx.x;
  const int b = blk >> 7, c = blk & 127;
  const int t = threadIdx.x;
  __shared__ float2 Gl2[500];                  // [tap][id] transposed
  for (int i = t; i < 500; i += 256){
    int j = i / 25, d = i - (i/25)*25;
    Gl2[d*20 + j] = G[((size_t)(b*CC + c))*500 + i];
  }
  __syncthreads();
  const float ga = 1.f/(1.f + __expf(-bgam[0]));
  const float ba = 1.f/(1.f + __expf(-bbet[0]));
  const float mn = mean[b*CC + c], rs = rstd[b*CC + c];
  const float cg = cgb[c], cb = cbb[c], sg = sgb[c], sb = sbb[c];
  const float* xp  = xin + (size_t)(b*CC + c)*NPIX;
  const unsigned short* spg = spade + (size_t)(b*256 + c)*NPIX;
  const unsigned short* spb = spade + (size_t)(b*256 + c + 128)*NPIX;
  float* op = out + (size_t)(b*CC + c)*NPIX;
  const int* idb = ids + b*PCELLS;
  for (int p2 = t; p2 < NPIX/2; p2 += 256){
    int p = p2*2;
    int y = p >> 7, x = p & 127;
    float ag0=0.f, ab0=0.f, ag1=0.f, ab1=0.f;
    #pragma unroll
    for (int dy = 0; dy < 5; ++dy){
      const int* row = idb + (y+dy)*HP + x;    // 8B-aligned (even offset)
      int2 v01 = *(const int2*)(row);
      int2 v23 = *(const int2*)(row + 2);
      int2 v45 = *(const int2*)(row + 4);
      int idv[6] = {v01.x, v01.y, v23.x, v23.y, v45.x, v45.y};
      #pragma unroll
      for (int dx = 0; dx < 5; ++dx){
        float2 g0 = Gl2[(dy*5+dx)*20 + idv[dx]];
        float2 g1 = Gl2[(dy*5+dx)*20 + idv[dx+1]];
        ag0 += g0.x; ab0 += g0.y;
        ag1 += g1.x; ab1 += g1.y;
      }
    }
    unsigned sg2 = *(const unsigned*)(spg + p);
    unsigned sb2 = *(const unsigned*)(spb + p);
    float2 xv = *(const float2*)(xp + p);
    float gf0 = ga*(ag0 + cg) + (1.f - ga)*(bflo(sg2) + sg);
    float bf0 = ba*(ab0 + cb) + (1.f - ba)*(bflo(sb2) + sb);
    float gf1 = ga*(ag1 + cg) + (1.f - ga)*(bfhi(sg2) + sg);
    float bf1 = ba*(ab1 + cb) + (1.f - ba)*(bfhi(sb2) + sb);
    float2 ov;
    ov.x = (xv.x - mn)*rs*(1.f + gf0) + bf0;
    ov.y = (xv.y - mn)*rs*(1.f + gf1) + bf1;
    *(float2*)(op + p) = ov;
  }
}

extern "C" void kernel_launch(void* const* d_in, const int* in_sizes, int n_in,
                              void* d_out, int out_size, void* d_ws, size_t ws_size,
                              hipStream_t stream){
  const float* x    = (const float*)d_in[0];
  const float* seg  = (const float*)d_in[1];
  const float* sty  = (const float*)d_in[2];
  const float* fcw  = (const float*)d_in[3];
  const float* fcb  = (const float*)d_in[4];
  const float* cgw  = (const float*)d_in[5];
  const float* cgb  = (const float*)d_in[6];
  const float* cbw  = (const float*)d_in[7];
  const float* cbb  = (const float*)d_in[8];
  const float* ssw  = (const float*)d_in[9];
  const float* ssb  = (const float*)d_in[10];
  const float* sgw  = (const float*)d_in[11];
  const float* sgb  = (const float*)d_in[12];
  const float* sbw  = (const float*)d_in[13];
  const float* sbb  = (const float*)d_in[14];
  const float* bgam = (const float*)d_in[15];
  const float* bbet = (const float*)d_in[16];
  float* out = (float*)d_out;

  char* ws = (char*)d_ws;
  size_t o = 0;
  auto alloc = [&](size_t n){ size_t r = o; o = (o + n + 255) & ~(size_t)255; return r; };
  float* mean          = (float*)(ws + alloc(512*4));
  float* rstd          = (float*)(ws + alloc(512*4));
  int*   ids           = (int*)  (ws + alloc((size_t)NCELL*4));
  float* mu            = (float*)(ws + alloc((size_t)BB*LL*SS*4));
  float2* G            = (float2*)(ws + alloc((size_t)BB*CC*500*8));
  unsigned short* Tt   = (unsigned short*)(ws + alloc((size_t)20*25*SS*2));
  unsigned char* W2q   = (unsigned char*)(ws + alloc((size_t)256*12800));
  unsigned char* actv8 = (unsigned char*)(ws + alloc((size_t)NCELL*SS));
  unsigned short* spade= (unsigned short*)(ws + alloc((size_t)BB*256*NPIX*2 < (size_t)2*128*25*512*4
                                                      ? (size_t)2*128*25*512*4
                                                      : (size_t)BB*256*NPIX*2));
  // Wt tables alias spade region (consumed by k_gtab before k_conv writes it)
  float* Wtg = (float*)spade;
  float* Wtb = (float*)spade + (size_t)128*25*512;
  (void)o; (void)ws_size; (void)in_sizes; (void)n_in; (void)out_size; (void)sty;

  k_pre  <<<dim3(2373), dim3(256), 0, stream>>>(x, mean, rstd, seg, ids,
                                                sty, fcw, fcb, mu,
                                                cgw, cbw, Wtg, Wtb,
                                                ssw, Tt, sgw, sbw, (unsigned*)W2q);
  k_gtab <<<dim3(512),  dim3(256), 0, stream>>>(mu, Wtg, Wtb, G);
  k_actv <<<dim3(1092), dim3(512), 0, stream>>>(ids, Tt, ssb, (uint2*)actv8);
  k_conv <<<dim3(256),  dim3(512), 0, stream>>>(actv8, W2q, spade);
  k_final<<<dim3(512),  dim3(256), 0, stream>>>(x, ids, G, spade, mean, rstd,
                                                cgb, cbb, sgb, sbb, bgam, bbet, out);
}

// Round 10
// 365.059 us; speedup vs baseline: 1.8581x; 1.1042x over previous
//
#include <hip/hip_runtime.h>
#include <stdint.h>

#define BB 4
#define CC 128
#define HH 128
#define WW 128
#define LL 19
#define SS 512
#define HP 132
#define NPIX (HH*WW)      // 16384
#define PCELLS (HP*HP)    // 17424
#define NCELL (BB*PCELLS) // 69696

#define SA 192.0f
#define SW 1024.0f
#define INVQ (1.0f/(SA*SW))
#define INVSW (1.0f/SW)

typedef float f32x4 __attribute__((ext_vector_type(4)));
typedef int   i32x4 __attribute__((ext_vector_type(4)));
typedef short s16x8 __attribute__((ext_vector_type(8)));

#define AS1Q __attribute__((address_space(1)))
#define AS3Q __attribute__((address_space(3)))
#define MEMFENCE asm volatile("" ::: "memory")

__device__ __forceinline__ void gld16(const void* g, void* l){
  __builtin_amdgcn_global_load_lds((const AS1Q void*)g, (AS3Q void*)l, 16, 0, 0);
}

__device__ inline unsigned short f2bf(float v){
  unsigned u = __float_as_uint(v);
  return (unsigned short)((u + 0x7fffu + ((u >> 16) & 1u)) >> 16);
}
__device__ inline float bflo(unsigned u){ return __uint_as_float(u << 16); }
__device__ inline float bfhi(unsigned u){ return __uint_as_float(u & 0xffff0000u); }

// ------- fused pre-pass -----------------------------------------------
// blocks: [0,512) stats | [512,785) ids | [785,861) fc |
//         [861,1117) w2t LDS-transpose | [1117,2117) ttab-i16 |
//         [2117,2373) w2q int8 LDS-transpose
__global__ __launch_bounds__(256) void k_pre(
                      const float* __restrict__ x, float* __restrict__ mean,
                      float* __restrict__ rstd,
                      const float* __restrict__ seg, int* __restrict__ ids,
                      const float* __restrict__ style, const float* __restrict__ fcw,
                      const float* __restrict__ fcb, float* __restrict__ mu,
                      const float* __restrict__ cgw, const float* __restrict__ cbw,
                      float* __restrict__ Wtg, float* __restrict__ Wtb,
                      const float* __restrict__ ssw, short* __restrict__ Tt16,
                      const float* __restrict__ sgw, const float* __restrict__ sbw,
                      unsigned* __restrict__ W2q){
  __shared__ float shmem[12800];               // 51.2 KB
  const int blk = blockIdx.x;
  const int t = threadIdx.x;
  if (blk < 512){
    const int bc = blk;
    const int w = t >> 6, lane = t & 63;
    const float4* xv = (const float4*)(x + (size_t)bc * NPIX);
    float s = 0.f, q = 0.f;
    for (int i = t; i < NPIX/4; i += 256){
      float4 v = xv[i];
      s += v.x + v.y + v.z + v.w;
      q += v.x*v.x + v.y*v.y + v.z*v.z + v.w*v.w;
    }
    #pragma unroll
    for (int off = 32; off; off >>= 1){ s += __shfl_down(s, off); q += __shfl_down(q, off); }
    if (lane == 0){ shmem[w] = s; shmem[4 + w] = q; }
    __syncthreads();
    if (t == 0){
      float S = shmem[0]+shmem[1]+shmem[2]+shmem[3];
      float Q = shmem[4]+shmem[5]+shmem[6]+shmem[7];
      float mn = S * (1.f/16384.f);
      float var = Q * (1.f/16384.f) - mn*mn;
      mean[bc] = mn;
      rstd[bc] = rsqrtf(var + 1e-5f);
    }
  } else if (blk < 785){
    int idx = (blk - 512)*256 + t;
    if (idx >= NCELL) return;
    int b = idx / PCELLS; int rem = idx - b*PCELLS;
    int r = rem / HP;     int cp = rem - r*HP;
    int id = LL;
    if (r >= 2 && r <= 129 && cp >= 2 && cp <= 129){
      int p = (r-2)*WW + (cp-2);
      const float* sp = seg + (size_t)b*LL*NPIX + p;
      id = 0;
      for (int j = 0; j < LL; ++j){
        if (sp[(size_t)j*NPIX] > 0.5f){ id = j; break; }
      }
    }
    ids[idx] = id;
  } else if (blk < 861){
    const int jb = blk - 785;
    const int j = jb >> 2, part = jb & 3;
    const int w = t >> 6, lane = t & 63;
    float (*s_s)[SS] = (float(*)[SS])shmem;
    for (int i = t; i < 4*SS; i += 256){
      int b = i >> 9, e = i & 511;
      s_s[b][e] = style[(size_t)(b*LL + j)*SS + e];
    }
    __syncthreads();
    for (int e = part*128 + w; e < part*128 + 128; e += 4){
      const float* row = fcw + ((size_t)(j*SS + e))*SS;
      float a0=0.f, a1=0.f, a2=0.f, a3=0.f;
      #pragma unroll
      for (int i = 0; i < 8; ++i){
        int d = lane + i*64; float rv = row[d];
        a0 += s_s[0][d]*rv; a1 += s_s[1][d]*rv;
        a2 += s_s[2][d]*rv; a3 += s_s[3][d]*rv;
      }
      #pragma unroll
      for (int off = 32; off; off >>= 1){
        a0 += __shfl_down(a0,off); a1 += __shfl_down(a1,off);
        a2 += __shfl_down(a2,off); a3 += __shfl_down(a3,off);
      }
      if (lane == 0){
        float fb = fcb[j*SS + e];
        mu[(size_t)(0*LL+j)*SS + e] = fmaxf(a0+fb, 0.f);
        mu[(size_t)(1*LL+j)*SS + e] = fmaxf(a1+fb, 0.f);
        mu[(size_t)(2*LL+j)*SS + e] = fmaxf(a2+fb, 0.f);
        mu[(size_t)(3*LL+j)*SS + e] = fmaxf(a3+fb, 0.f);
      }
    }
  } else if (blk < 1117){
    // ---- w2t: coalesced read -> LDS -> coalesced transposed write ----
    int pb = blk - 861;                        // 0..255
    int c = pb >> 1;
    const float* src = ((pb & 1) ? cbw : cgw) + (size_t)c*12800;  // [e][d]
    float* dst = ((pb & 1) ? Wtb : Wtg) + (size_t)c*12800;        // [d][e]
    for (int i = t; i < 12800; i += 256) shmem[i] = src[i];
    __syncthreads();
    for (int i = t; i < 12800; i += 256){
      int dd = i >> 9, e = i & 511;            // i = dd*512 + e
      dst[i] = shmem[e*25 + dd];               // stride-25 LDS read: conflict-free
    }
  } else if (blk < 2117){
    int idx = (blk-1117)*256 + t;              // 20*25*512
    int s = idx & 511; int rest = idx >> 9;
    int j = rest / 25, d = rest - (rest/25)*25;
    float v = 0.f;
    if (j < LL) v = ssw[((size_t)s*LL + j)*25 + d];
    int q = (int)rintf(v * SW);
    q = q > 32767 ? 32767 : (q < -32768 ? -32768 : q);
    Tt16[idx] = (short)q;
  } else {
    // ---- w2q int8: coalesced read -> LDS -> quantized reorder write ----
    int cpr = blk - 2117;                      // 0..255
    const float* w = (cpr < 128) ? sgw : sbw;
    int c = cpr & 127;
    const float* src = w + (size_t)c*12800;    // [e][d]
    for (int i = t; i < 12800; i += 256) shmem[i] = src[i];
    __syncthreads();
    for (int wd = t; wd < 3200; wd += 256){
      int r4 = wd*4; int tt = r4 >> 6; int k0 = r4 & 63;
      int schunk = tt/25, tap = tt - schunk*25;
      unsigned pack = 0;
      #pragma unroll
      for (int i = 0; i < 4; ++i){
        int s = schunk*64 + k0 + i;
        int q = (int)rintf(shmem[s*25 + tap] * SW);
        q = q > 127 ? 127 : (q < -127 ? -127 : q);
        pack |= ((unsigned)(q & 0xFF)) << (8*i);
      }
      W2q[(size_t)cpr*3200 + wd] = pack;
    }
  }
}

// ---------------- G table: wave-per-output coalesced dot ------------------
__global__ void k_gtab(const float* __restrict__ mu, const float* __restrict__ Wtg,
                       const float* __restrict__ Wtb, float2* __restrict__ G){
  const int blk = blockIdx.x;
  const int b = blk >> 7, c = blk & 127;
  const int t = threadIdx.x, w = t >> 6, lane = t & 63;
  __shared__ float mu_s[LL*SS];
  for (int i = t; i < LL*SS; i += 256) mu_s[i] = mu[(size_t)b*LL*SS + i];
  __syncthreads();
  for (int i = 0; i < 125; ++i){
    int o = i*4 + w;
    int j = o / 25, d = o - (o/25)*25;
    float ag = 0.f, ab = 0.f;
    if (j < LL){
      const float4* wg4 = (const float4*)(Wtg + ((size_t)c*25 + d)*SS);
      const float4* wb4 = (const float4*)(Wtb + ((size_t)c*25 + d)*SS);
      const float4* m4p = (const float4*)(mu_s + j*SS);
      #pragma unroll
      for (int rp = 0; rp < 2; ++rp){
        int e4 = rp*64 + lane;
        float4 m4 = m4p[e4];
        float4 wv = wg4[e4];
        ag += m4.x*wv.x + m4.y*wv.y + m4.z*wv.z + m4.w*wv.w;
        float4 wv2 = wb4[e4];
        ab += m4.x*wv2.x + m4.y*wv2.y + m4.z*wv2.z + m4.w*wv2.w;
      }
      #pragma unroll
      for (int off = 32; off; off >>= 1){ ag += __shfl_down(ag, off); ab += __shfl_down(ab, off); }
    }
    if (lane == 0) G[((size_t)(b*CC + c))*500 + o] = make_float2(ag, ab);
  }
}

// ------ actv: i16 table, packed v_pk_add_i16 accumulation, 64-ch slices ---
__global__ __launch_bounds__(512) void k_actv(
    const int* __restrict__ ids, const short* __restrict__ Tt16,
    const float* __restrict__ ssb, uint2* __restrict__ actv8){
  __shared__ short Tl[500*72];                 // 72000 B (rows padded to 144B)
  const int t = threadIdx.x, w = t >> 6, lane = t & 63;
  const int cs  = blockIdx.x & 7;              // 64-ch slice
  const int cg0 = blockIdx.x >> 3;             // cell group (256 cells)
  for (int i = t; i < 4000; i += 512){         // 500 rows x 8 int4 (128B slice)
    int row = i >> 3, sub = i & 7;
    int4 v = *(const int4*)(Tt16 + (size_t)row*512 + cs*64 + sub*8);
    *(int4*)(Tl + row*72 + sub*8) = v;
  }
  __syncthreads();
  const int chsub = lane & 7;                  // 8-ch group within slice
  const int csub  = lane >> 3;                 // 8 cells per wave
  float bias[8];
  #pragma unroll
  for (int i = 0; i < 8; ++i) bias[i] = ssb[cs*64 + chsub*8 + i];
  for (int it = 0; it < 4; ++it){
    int cell = cg0*256 + it*64 + w*8 + csub;
    if (cell >= NCELL) break;
    int b = cell / PCELLS; int rem = cell - b*PCELLS;
    int r = rem / HP;      int cp = rem - r*HP;
    uint2 outv = {0u, 0u};
    if (r >= 2 && r <= 129 && cp >= 2 && cp <= 129){
      const int* idb = ids + b*PCELLS + (r-2)*HP + (cp-2);
      s16x8 acc = {0,0,0,0,0,0,0,0};           // max |sum| <= 25*~130, fits i16
      #pragma unroll
      for (int dy = 0; dy < 5; ++dy){
        const int* row5 = idb + dy*HP;
        #pragma unroll
        for (int dx = 0; dx < 5; ++dx){
          int id = row5[dx];
          acc += *(const s16x8*)(Tl + (id*25 + dy*5 + dx)*72 + chsub*8);
        }
      }
      unsigned q[8];
      #pragma unroll
      for (int i = 0; i < 8; ++i){
        float a = (float)acc[i] * INVSW + bias[i];
        int v = (int)(fmaxf(a, 0.f)*SA + 0.5f);
        q[i] = (unsigned)(v > 127 ? 127 : v);
      }
      outv.x = q[0] | (q[1]<<8) | (q[2]<<16) | (q[3]<<24);
      outv.y = q[4] | (q[5]<<8) | (q[6]<<16) | (q[7]<<24);
    }
    actv8[(size_t)cell*64 + cs*8 + chsub] = outv;   // bytes: cell*512 + cs*64 + chsub*8
  }
}

// ------- big conv int8: BK=64, 200 steps, 1 barrier/step, ping-pong -------
__global__ __launch_bounds__(512, 2) void k_conv(
    const unsigned char* __restrict__ actv8,   // i8 [B][132][132][512]
    const unsigned char* __restrict__ W2q,     // i8 [256][12800] (tt-major)
    unsigned short* __restrict__ spade)        // bf16 [B][256][128][128]
{
  __shared__ int4 lds4[131072/16];             // 128 KiB: 4 bufs x (A 16K + B 16K)
  char* ldsb = (char*)lds4;
  const int bid = blockIdx.x;
  const int blk = (bid & 7)*32 + (bid >> 3);   // bijective XCD swizzle
  const int b  = blk >> 6;
  const int y0 = (blk & 63) * 2;
  const int t  = threadIdx.x;
  const int lane = t & 63;
  const int w  = t >> 6;
  const int wr = w >> 2, wc = w & 3;
  const int li = lane & 15, q = lane >> 4;

  const int lsub  = lane >> 2;
  const int s_src = (lane & 3) ^ ((lane >> 3) & 3);
  const bool isA  = (w < 4);
  const char* p0[4];
  int ldsrel[4];
  #pragma unroll
  for (int l = 0; l < 4; ++l){
    int row = (isA ? w : (w - 4)) * 64 + l*16 + lsub;
    if (isA){
      int y = y0 + (row >> 7), x = row & 127;
      p0[l] = (const char*)(actv8 + (((size_t)b*HP + y)*HP + x)*SS + s_src*16);
    } else {
      p0[l] = (const char*)(W2q + (size_t)row*12800 + s_src*16);
    }
    ldsrel[l] = w*4096 + l*1024 + lane*16;
  }

  auto stage_tt = [&](int tt){               // 4 x 16B loads/thread
    int schunk = tt / 25; int tap = tt - schunk*25;
    int dy = tap / 5, dx = tap - dy*5;
    size_t offA = (size_t)(dy*HP + dx)*SS + (size_t)schunk*64;
    size_t off = isA ? offA : (size_t)tt * 64;
    char* base = ldsb + ((tt & 3) * 32768);
    #pragma unroll
    for (int l = 0; l < 4; ++l)
      gld16(p0[l] + off, base + ldsrel[l]);
  };

  i32x4 acc[8][4];
  #pragma unroll
  for (int m = 0; m < 8; ++m)
    #pragma unroll
    for (int n = 0; n < 4; ++n) acc[m][n] = (i32x4){0,0,0,0};

  const int swz  = (q ^ ((li >> 1) & 3)) * 16;
  const int arel = (wr*128 + li)*64 + swz;
  const int brel = 16384 + (wc*64 + li)*64 + swz;

  i32x4 a03[2][4], bv[2][4], a47[4];

  stage_tt(0); stage_tt(1); stage_tt(2);
  asm volatile("s_waitcnt vmcnt(8)" ::: "memory");
  __builtin_amdgcn_s_barrier();
  MEMFENCE;
  #pragma unroll
  for (int m = 0; m < 4; ++m) a03[0][m] = *(const i32x4*)(ldsb + arel + m*1024);
  #pragma unroll
  for (int n = 0; n < 4; ++n) bv[0][n]  = *(const i32x4*)(ldsb + brel + n*1024);

  for (int T2 = 0; T2 < 99; ++T2){
    #pragma unroll
    for (int half = 0; half < 2; ++half){
      const int T = 2*T2 + half;
      const char* buf  = ldsb + ((unsigned)T & 3u)*32768;
      const char* bufn = ldsb + ((unsigned)(T+1) & 3u)*32768;
      const int cur = half, nxt = half ^ 1;
      #pragma unroll
      for (int m = 0; m < 4; ++m) a47[m] = *(const i32x4*)(buf + arel + (m+4)*1024);
      MEMFENCE;
      asm volatile("s_waitcnt vmcnt(4)" ::: "memory");
      __builtin_amdgcn_s_barrier();
      MEMFENCE;
      if (T <= 196) stage_tt(T + 3);
      MEMFENCE;
      __builtin_amdgcn_s_setprio(1);
      #pragma unroll
      for (int m = 0; m < 4; ++m)
        #pragma unroll
        for (int n = 0; n < 4; ++n)
          acc[m][n] = __builtin_amdgcn_mfma_i32_16x16x64_i8(a03[cur][m], bv[cur][n], acc[m][n], 0, 0, 0);
      __builtin_amdgcn_s_setprio(0);
      MEMFENCE;
      #pragma unroll
      for (int m = 0; m < 4; ++m) a03[nxt][m] = *(const i32x4*)(bufn + arel + m*1024);
      #pragma unroll
      for (int n = 0; n < 4; ++n) bv[nxt][n]  = *(const i32x4*)(bufn + brel + n*1024);
      MEMFENCE;
      __builtin_amdgcn_s_setprio(1);
      #pragma unroll
      for (int m = 0; m < 4; ++m)
        #pragma unroll
        for (int n = 0; n < 4; ++n)
          acc[m+4][n] = __builtin_amdgcn_mfma_i32_16x16x64_i8(a47[m], bv[cur][n], acc[m+4][n], 0, 0, 0);
      __builtin_amdgcn_s_setprio(0);
      MEMFENCE;
    }
  }
  // T = 198
  {
    const char* buf  = ldsb + (198 & 3)*32768;
    const char* bufn = ldsb + (199 & 3)*32768;
    #pragma unroll
    for (int m = 0; m < 4; ++m) a47[m] = *(const i32x4*)(buf + arel + (m+4)*1024);
    MEMFENCE;
    asm volatile("s_waitcnt vmcnt(0)" ::: "memory");
    __builtin_amdgcn_s_barrier();
    MEMFENCE;
    #pragma unroll
    for (int m = 0; m < 4; ++m)
      #pragma unroll
      for (int n = 0; n < 4; ++n)
        acc[m][n] = __builtin_amdgcn_mfma_i32_16x16x64_i8(a03[0][m], bv[0][n], acc[m][n], 0, 0, 0);
    #pragma unroll
    for (int m = 0; m < 4; ++m) a03[1][m] = *(const i32x4*)(bufn + arel + m*1024);
    #pragma unroll
    for (int n = 0; n < 4; ++n) bv[1][n]  = *(const i32x4*)(bufn + brel + n*1024);
    #pragma unroll
    for (int m = 0; m < 4; ++m)
      #pragma unroll
      for (int n = 0; n < 4; ++n)
        acc[m+4][n] = __builtin_amdgcn_mfma_i32_16x16x64_i8(a47[m], bv[0][n], acc[m+4][n], 0, 0, 0);
  }
  // T = 199
  {
    const char* buf = ldsb + (199 & 3)*32768;
    #pragma unroll
    for (int m = 0; m < 4; ++m) a47[m] = *(const i32x4*)(buf + arel + (m+4)*1024);
    #pragma unroll
    for (int m = 0; m < 4; ++m)
      #pragma unroll
      for (int n = 0; n < 4; ++n)
        acc[m][n] = __builtin_amdgcn_mfma_i32_16x16x64_i8(a03[1][m], bv[1][n], acc[m][n], 0, 0, 0);
    #pragma unroll
    for (int m = 0; m < 4; ++m)
      #pragma unroll
      for (int n = 0; n < 4; ++n)
        acc[m+4][n] = __builtin_amdgcn_mfma_i32_16x16x64_i8(a47[m], bv[1][n], acc[m+4][n], 0, 0, 0);
  }

  // epilogue: dequant i32 -> f32, pack bf16
  const int xq4 = (lane >> 4) << 2;
  const int cq  = wc*64 + (lane & 15);
  #pragma unroll
  for (int m = 0; m < 8; ++m){
    int p = wr*128 + m*16 + xq4;
    int y = y0 + (p >> 7), x = p & 127;
    #pragma unroll
    for (int n = 0; n < 4; ++n){
      int cp = cq + n*16;
      i32x4 a = acc[m][n];
      uint2 pk;
      pk.x = (unsigned)f2bf((float)a.x * INVQ) | ((unsigned)f2bf((float)a.y * INVQ) << 16);
      pk.y = (unsigned)f2bf((float)a.z * INVQ) | ((unsigned)f2bf((float)a.w * INVQ) << 16);
      *(uint2*)(spade + (((size_t)(b*256 + cp))*HH + y)*WW + x) = pk;
    }
  }
}

// ---------------- final: paired-pixel gather + blend + IN apply -----------
__global__ void k_final(const float* __restrict__ xin, const int* __restrict__ ids,
                        const float2* __restrict__ G, const unsigned short* __restrict__ spade,
                        const float* __restrict__ mean, const float* __restrict__ rstd,
                        const float* __restrict__ cgb, const float* __restrict__ cbb,
                        const float* __restrict__ sgb, const float* __restrict__ sbb,
                        const float* __restrict__ bgam, const float* __restrict__ bbet,
                        float* __restrict__ out){
  const int blk = blockIdx.x;
  const int b = blk >> 7, c = blk & 127;
  const int t = threadIdx.x;
  __shared__ float2 Gl2[500];                  // [tap][id] transposed
  for (int i = t; i < 500; i += 256){
    int j = i / 25, d = i - (i/25)*25;
    Gl2[d*20 + j] = G[((size_t)(b*CC + c))*500 + i];
  }
  __syncthreads();
  const float ga = 1.f/(1.f + __expf(-bgam[0]));
  const float ba = 1.f/(1.f + __expf(-bbet[0]));
  const float mn = mean[b*CC + c], rs = rstd[b*CC + c];
  const float cg = cgb[c], cb = cbb[c], sg = sgb[c], sb = sbb[c];
  const float* xp  = xin + (size_t)(b*CC + c)*NPIX;
  const unsigned short* spg = spade + (size_t)(b*256 + c)*NPIX;
  const unsigned short* spb = spade + (size_t)(b*256 + c + 128)*NPIX;
  float* op = out + (size_t)(b*CC + c)*NPIX;
  const int* idb = ids + b*PCELLS;
  for (int p2 = t; p2 < NPIX/2; p2 += 256){
    int p = p2*2;
    int y = p >> 7, x = p & 127;
    float ag0=0.f, ab0=0.f, ag1=0.f, ab1=0.f;
    #pragma unroll
    for (int dy = 0; dy < 5; ++dy){
      const int* row = idb + (y+dy)*HP + x;    // 8B-aligned (even offset)
      int2 v01 = *(const int2*)(row);
      int2 v23 = *(const int2*)(row + 2);
      int2 v45 = *(const int2*)(row + 4);
      int idv[6] = {v01.x, v01.y, v23.x, v23.y, v45.x, v45.y};
      #pragma unroll
      for (int dx = 0; dx < 5; ++dx){
        float2 g0 = Gl2[(dy*5+dx)*20 + idv[dx]];
        float2 g1 = Gl2[(dy*5+dx)*20 + idv[dx+1]];
        ag0 += g0.x; ab0 += g0.y;
        ag1 += g1.x; ab1 += g1.y;
      }
    }
    unsigned sg2 = *(const unsigned*)(spg + p);
    unsigned sb2 = *(const unsigned*)(spb + p);
    float2 xv = *(const float2*)(xp + p);
    float gf0 = ga*(ag0 + cg) + (1.f - ga)*(bflo(sg2) + sg);
    float bf0 = ba*(ab0 + cb) + (1.f - ba)*(bflo(sb2) + sb);
    float gf1 = ga*(ag1 + cg) + (1.f - ga)*(bfhi(sg2) + sg);
    float bf1 = ba*(ab1 + cb) + (1.f - ba)*(bfhi(sb2) + sb);
    float2 ov;
    ov.x = (xv.x - mn)*rs*(1.f + gf0) + bf0;
    ov.y = (xv.y - mn)*rs*(1.f + gf1) + bf1;
    *(float2*)(op + p) = ov;
  }
}

extern "C" void kernel_launch(void* const* d_in, const int* in_sizes, int n_in,
                              void* d_out, int out_size, void* d_ws, size_t ws_size,
                              hipStream_t stream){
  const float* x    = (const float*)d_in[0];
  const float* seg  = (const float*)d_in[1];
  const float* sty  = (const float*)d_in[2];
  const float* fcw  = (const float*)d_in[3];
  const float* fcb  = (const float*)d_in[4];
  const float* cgw  = (const float*)d_in[5];
  const float* cgb  = (const float*)d_in[6];
  const float* cbw  = (const float*)d_in[7];
  const float* cbb  = (const float*)d_in[8];
  const float* ssw  = (const float*)d_in[9];
  const float* ssb  = (const float*)d_in[10];
  const float* sgw  = (const float*)d_in[11];
  const float* sgb  = (const float*)d_in[12];
  const float* sbw  = (const float*)d_in[13];
  const float* sbb  = (const float*)d_in[14];
  const float* bgam = (const float*)d_in[15];
  const float* bbet = (const float*)d_in[16];
  float* out = (float*)d_out;

  char* ws = (char*)d_ws;
  size_t o = 0;
  auto alloc = [&](size_t n){ size_t r = o; o = (o + n + 255) & ~(size_t)255; return r; };
  float* mean          = (float*)(ws + alloc(512*4));
  float* rstd          = (float*)(ws + alloc(512*4));
  int*   ids           = (int*)  (ws + alloc((size_t)NCELL*4));
  float* mu            = (float*)(ws + alloc((size_t)BB*LL*SS*4));
  float2* G            = (float2*)(ws + alloc((size_t)BB*CC*500*8));
  short* Tt16          = (short*)(ws + alloc((size_t)20*25*SS*2));
  unsigned char* W2q   = (unsigned char*)(ws + alloc((size_t)256*12800));
  unsigned char* actv8 = (unsigned char*)(ws + alloc((size_t)NCELL*SS));
  unsigned short* spade= (unsigned short*)(ws + alloc((size_t)BB*256*NPIX*2 < (size_t)2*128*25*512*4
                                                      ? (size_t)2*128*25*512*4
                                                      : (size_t)BB*256*NPIX*2));
  // Wt tables alias spade region (consumed by k_gtab before k_conv writes it)
  float* Wtg = (float*)spade;
  float* Wtb = (float*)spade + (size_t)128*25*512;
  (void)o; (void)ws_size; (void)in_sizes; (void)n_in; (void)out_size; (void)sty;

  k_pre  <<<dim3(2373), dim3(256), 0, stream>>>(x, mean, rstd, seg, ids,
                                                sty, fcw, fcb, mu,
                                                cgw, cbw, Wtg, Wtb,
                                                ssw, Tt16, sgw, sbw, (unsigned*)W2q);
  k_gtab <<<dim3(512),  dim3(256), 0, stream>>>(mu, Wtg, Wtb, G);
  k_actv <<<dim3(2184), dim3(512), 0, stream>>>(ids, Tt16, ssb, (uint2*)actv8);
  k_conv <<<dim3(256),  dim3(512), 0, stream>>>(actv8, W2q, spade);
  k_final<<<dim3(512),  dim3(256), 0, stream>>>(x, ids, G, spade, mean, rstd,
                                                cgb, cbb, sgb, sbb, bgam, bbet, out);
}

// Round 11
// 343.044 us; speedup vs baseline: 1.9774x; 1.0642x over previous
//
#include <hip/hip_runtime.h>
#include <stdint.h>

#define BB 4
#define CC 128
#define HH 128
#define WW 128
#define LL 19
#define SS 512
#define HP 132
#define NPIX (HH*WW)      // 16384
#define PCELLS (HP*HP)    // 17424
#define NCELL (BB*PCELLS) // 69696

#define SA 192.0f
#define SW 1024.0f
#define INVQ (1.0f/(SA*SW))
#define INVSW (1.0f/SW)

typedef float f32x4 __attribute__((ext_vector_type(4)));
typedef int   i32x4 __attribute__((ext_vector_type(4)));
typedef short s16x8 __attribute__((ext_vector_type(8)));

#define AS1Q __attribute__((address_space(1)))
#define AS3Q __attribute__((address_space(3)))
#define MEMFENCE asm volatile("" ::: "memory")

__device__ __forceinline__ void gld16(const void* g, void* l){
  __builtin_amdgcn_global_load_lds((const AS1Q void*)g, (AS3Q void*)l, 16, 0, 0);
}

__device__ inline unsigned short f2bf(float v){
  unsigned u = __float_as_uint(v);
  return (unsigned short)((u + 0x7fffu + ((u >> 16) & 1u)) >> 16);
}
__device__ inline float bflo(unsigned u){ return __uint_as_float(u << 16); }
__device__ inline float bfhi(unsigned u){ return __uint_as_float(u & 0xffff0000u); }

// ------- fused pre-pass -----------------------------------------------
// blocks: [0,512) stats | [512,785) ids | [785,861) fc |
//         [861,1117) w2t->bf16 LDS-transpose | [1117,2117) ttab-i16 |
//         [2117,2373) w2q int8 LDS-transpose
__global__ __launch_bounds__(256) void k_pre(
                      const float* __restrict__ x, float* __restrict__ mean,
                      float* __restrict__ rstd,
                      const float* __restrict__ seg, int* __restrict__ ids,
                      const float* __restrict__ style, const float* __restrict__ fcw,
                      const float* __restrict__ fcb, float* __restrict__ mu,
                      const float* __restrict__ cgw, const float* __restrict__ cbw,
                      unsigned short* __restrict__ Wtg16, unsigned short* __restrict__ Wtb16,
                      const float* __restrict__ ssw, short* __restrict__ Tt16,
                      const float* __restrict__ sgw, const float* __restrict__ sbw,
                      unsigned* __restrict__ W2q){
  __shared__ float shmem[12800];               // 51.2 KB
  const int blk = blockIdx.x;
  const int t = threadIdx.x;
  if (blk < 512){
    const int bc = blk;
    const int w = t >> 6, lane = t & 63;
    const float4* xv = (const float4*)(x + (size_t)bc * NPIX);
    float s = 0.f, q = 0.f;
    for (int i = t; i < NPIX/4; i += 256){
      float4 v = xv[i];
      s += v.x + v.y + v.z + v.w;
      q += v.x*v.x + v.y*v.y + v.z*v.z + v.w*v.w;
    }
    #pragma unroll
    for (int off = 32; off; off >>= 1){ s += __shfl_down(s, off); q += __shfl_down(q, off); }
    if (lane == 0){ shmem[w] = s; shmem[4 + w] = q; }
    __syncthreads();
    if (t == 0){
      float S = shmem[0]+shmem[1]+shmem[2]+shmem[3];
      float Q = shmem[4]+shmem[5]+shmem[6]+shmem[7];
      float mn = S * (1.f/16384.f);
      float var = Q * (1.f/16384.f) - mn*mn;
      mean[bc] = mn;
      rstd[bc] = rsqrtf(var + 1e-5f);
    }
  } else if (blk < 785){
    int idx = (blk - 512)*256 + t;
    if (idx >= NCELL) return;
    int b = idx / PCELLS; int rem = idx - b*PCELLS;
    int r = rem / HP;     int cp = rem - r*HP;
    int id = LL;
    if (r >= 2 && r <= 129 && cp >= 2 && cp <= 129){
      int p = (r-2)*WW + (cp-2);
      const float* sp = seg + (size_t)b*LL*NPIX + p;
      id = 0;
      for (int j = 0; j < LL; ++j){
        if (sp[(size_t)j*NPIX] > 0.5f){ id = j; break; }
      }
    }
    ids[idx] = id;
  } else if (blk < 861){
    const int jb = blk - 785;
    const int j = jb >> 2, part = jb & 3;
    const int w = t >> 6, lane = t & 63;
    float (*s_s)[SS] = (float(*)[SS])shmem;
    for (int i = t; i < 4*SS; i += 256){
      int b = i >> 9, e = i & 511;
      s_s[b][e] = style[(size_t)(b*LL + j)*SS + e];
    }
    __syncthreads();
    for (int e = part*128 + w; e < part*128 + 128; e += 4){
      const float* row = fcw + ((size_t)(j*SS + e))*SS;
      float a0=0.f, a1=0.f, a2=0.f, a3=0.f;
      #pragma unroll
      for (int i = 0; i < 8; ++i){
        int d = lane + i*64; float rv = row[d];
        a0 += s_s[0][d]*rv; a1 += s_s[1][d]*rv;
        a2 += s_s[2][d]*rv; a3 += s_s[3][d]*rv;
      }
      #pragma unroll
      for (int off = 32; off; off >>= 1){
        a0 += __shfl_down(a0,off); a1 += __shfl_down(a1,off);
        a2 += __shfl_down(a2,off); a3 += __shfl_down(a3,off);
      }
      if (lane == 0){
        float fb = fcb[j*SS + e];
        mu[(size_t)(0*LL+j)*SS + e] = fmaxf(a0+fb, 0.f);
        mu[(size_t)(1*LL+j)*SS + e] = fmaxf(a1+fb, 0.f);
        mu[(size_t)(2*LL+j)*SS + e] = fmaxf(a2+fb, 0.f);
        mu[(size_t)(3*LL+j)*SS + e] = fmaxf(a3+fb, 0.f);
      }
    }
  } else if (blk < 1117){
    // ---- w2t: coalesced read -> LDS -> bf16 transposed write ----
    int pb = blk - 861;                        // 0..255
    int c = pb >> 1;
    const float* src = ((pb & 1) ? cbw : cgw) + (size_t)c*12800;        // [e][d]
    unsigned short* dst = ((pb & 1) ? Wtb16 : Wtg16) + (size_t)c*12800; // [d][e]
    for (int i = t; i < 12800; i += 256) shmem[i] = src[i];
    __syncthreads();
    for (int i = t; i < 12800; i += 256){
      int dd = i >> 9, e = i & 511;            // i = dd*512 + e
      dst[i] = f2bf(shmem[e*25 + dd]);         // stride-25 LDS read: conflict-free
    }
  } else if (blk < 2117){
    int idx = (blk-1117)*256 + t;              // 20*25*512
    int s = idx & 511; int rest = idx >> 9;
    int j = rest / 25, d = rest - (rest/25)*25;
    float v = 0.f;
    if (j < LL) v = ssw[((size_t)s*LL + j)*25 + d];
    int q = (int)rintf(v * SW);
    q = q > 32767 ? 32767 : (q < -32768 ? -32768 : q);
    Tt16[idx] = (short)q;
  } else {
    // ---- w2q int8: coalesced read -> LDS -> quantized reorder write ----
    int cpr = blk - 2117;                      // 0..255
    const float* w = (cpr < 128) ? sgw : sbw;
    int c = cpr & 127;
    const float* src = w + (size_t)c*12800;    // [e][d]
    for (int i = t; i < 12800; i += 256) shmem[i] = src[i];
    __syncthreads();
    for (int wd = t; wd < 3200; wd += 256){
      int r4 = wd*4; int tt = r4 >> 6; int k0 = r4 & 63;
      int schunk = tt/25, tap = tt - schunk*25;
      unsigned pack = 0;
      #pragma unroll
      for (int i = 0; i < 4; ++i){
        int s = schunk*64 + k0 + i;
        int q = (int)rintf(shmem[s*25 + tap] * SW);
        q = q > 127 ? 127 : (q < -127 ? -127 : q);
        pack |= ((unsigned)(q & 0xFF)) << (8*i);
      }
      W2q[(size_t)cpr*3200 + wd] = pack;
    }
  }
}

// ------- merged mid-pass: gtab [0,512) | actv [512,2696) ------------------
__global__ __launch_bounds__(512) void k_mid(
    const float* __restrict__ mu, const unsigned short* __restrict__ Wtg16,
    const unsigned short* __restrict__ Wtb16, float2* __restrict__ G,
    const int* __restrict__ ids, const short* __restrict__ Tt16,
    const float* __restrict__ ssb, uint2* __restrict__ actv8){
  __shared__ char smem[72000];
  const int blk = blockIdx.x;
  const int t = threadIdx.x, w = t >> 6, lane = t & 63;
  if (blk < 512){
    // ---- G table: wave-per-output, bf16 weights ----
    float* mu_s = (float*)smem;
    const int b = blk >> 7, c = blk & 127;
    for (int i = t; i < LL*SS; i += 512) mu_s[i] = mu[(size_t)b*LL*SS + i];
    __syncthreads();
    for (int i = 0; i < 63; ++i){
      int o = i*8 + w;                         // wave-uniform
      if (o >= 500) break;
      int j = o / 25, d = o - (o/25)*25;
      float ag = 0.f, ab = 0.f;
      if (j < LL){
        uint4 wg = *(const uint4*)(Wtg16 + ((size_t)c*25 + d)*SS + lane*8);
        uint4 wb = *(const uint4*)(Wtb16 + ((size_t)c*25 + d)*SS + lane*8);
        const float* mp = mu_s + j*SS + lane*8;
        float4 m0 = *(const float4*)mp;
        float4 m1 = *(const float4*)(mp + 4);
        ag = m0.x*bflo(wg.x) + m0.y*bfhi(wg.x) + m0.z*bflo(wg.y) + m0.w*bfhi(wg.y)
           + m1.x*bflo(wg.z) + m1.y*bfhi(wg.z) + m1.z*bflo(wg.w) + m1.w*bfhi(wg.w);
        ab = m0.x*bflo(wb.x) + m0.y*bfhi(wb.x) + m0.z*bflo(wb.y) + m0.w*bfhi(wb.y)
           + m1.x*bflo(wb.z) + m1.y*bfhi(wb.z) + m1.z*bflo(wb.w) + m1.w*bfhi(wb.w);
      }
      #pragma unroll
      for (int off = 32; off; off >>= 1){ ag += __shfl_down(ag, off); ab += __shfl_down(ab, off); }
      if (lane == 0) G[((size_t)(b*CC + c))*500 + o] = make_float2(ag, ab);
    }
  } else {
    // ---- actv: i16 table, packed adds, 64-ch slices ----
    short* Tl = (short*)smem;                  // 500 x 72 shorts
    const int ab2 = blk - 512;
    const int cs  = ab2 & 7;                   // 64-ch slice
    const int cg0 = ab2 >> 3;                  // cell group (256 cells)
    for (int i = t; i < 4000; i += 512){       // 500 rows x 8 int4
      int row = i >> 3, sub = i & 7;
      int4 v = *(const int4*)(Tt16 + (size_t)row*512 + cs*64 + sub*8);
      *(int4*)(Tl + row*72 + sub*8) = v;
    }
    __syncthreads();
    const int chsub = lane & 7;
    const int csub  = lane >> 3;
    float bias[8];
    #pragma unroll
    for (int i = 0; i < 8; ++i) bias[i] = ssb[cs*64 + chsub*8 + i];
    for (int it = 0; it < 4; ++it){
      int cell = cg0*256 + it*64 + w*8 + csub;
      if (cell >= NCELL) break;
      int b = cell / PCELLS; int rem = cell - b*PCELLS;
      int r = rem / HP;      int cp = rem - r*HP;
      uint2 outv = {0u, 0u};
      if (r >= 2 && r <= 129 && cp >= 2 && cp <= 129){
        const int* idb = ids + b*PCELLS + (r-2)*HP + (cp-2);
        s16x8 acc = {0,0,0,0,0,0,0,0};
        #pragma unroll
        for (int dy = 0; dy < 5; ++dy){
          const int* row5 = idb + dy*HP;
          #pragma unroll
          for (int dx = 0; dx < 5; ++dx){
            int id = row5[dx];
            acc += *(const s16x8*)(Tl + (id*25 + dy*5 + dx)*72 + chsub*8);
          }
        }
        unsigned q[8];
        #pragma unroll
        for (int i = 0; i < 8; ++i){
          float a = (float)acc[i] * INVSW + bias[i];
          int v = (int)(fmaxf(a, 0.f)*SA + 0.5f);
          q[i] = (unsigned)(v > 127 ? 127 : v);
        }
        outv.x = q[0] | (q[1]<<8) | (q[2]<<16) | (q[3]<<24);
        outv.y = q[4] | (q[5]<<8) | (q[6]<<16) | (q[7]<<24);
      }
      actv8[(size_t)cell*64 + cs*8 + chsub] = outv;
    }
  }
}

// ------- big conv int8: BK=64, 200 steps, 1 barrier/step, ping-pong -------
__global__ __launch_bounds__(512, 2) void k_conv(
    const unsigned char* __restrict__ actv8,   // i8 [B][132][132][512]
    const unsigned char* __restrict__ W2q,     // i8 [256][12800] (tt-major)
    unsigned short* __restrict__ spade)        // bf16 [B][256][128][128]
{
  __shared__ int4 lds4[131072/16];             // 128 KiB: 4 bufs x (A 16K + B 16K)
  char* ldsb = (char*)lds4;
  const int bid = blockIdx.x;
  const int blk = (bid & 7)*32 + (bid >> 3);   // bijective XCD swizzle
  const int b  = blk >> 6;
  const int y0 = (blk & 63) * 2;
  const int t  = threadIdx.x;
  const int lane = t & 63;
  const int w  = t >> 6;
  const int wr = w >> 2, wc = w & 3;
  const int li = lane & 15, q = lane >> 4;

  const int lsub  = lane >> 2;
  const int s_src = (lane & 3) ^ ((lane >> 3) & 3);
  const bool isA  = (w < 4);
  const char* p0[4];
  int ldsrel[4];
  #pragma unroll
  for (int l = 0; l < 4; ++l){
    int row = (isA ? w : (w - 4)) * 64 + l*16 + lsub;
    if (isA){
      int y = y0 + (row >> 7), x = row & 127;
      p0[l] = (const char*)(actv8 + (((size_t)b*HP + y)*HP + x)*SS + s_src*16);
    } else {
      p0[l] = (const char*)(W2q + (size_t)row*12800 + s_src*16);
    }
    ldsrel[l] = w*4096 + l*1024 + lane*16;
  }

  auto stage_tt = [&](int tt){               // 4 x 16B loads/thread
    int schunk = tt / 25; int tap = tt - schunk*25;
    int dy = tap / 5, dx = tap - dy*5;
    size_t offA = (size_t)(dy*HP + dx)*SS + (size_t)schunk*64;
    size_t off = isA ? offA : (size_t)tt * 64;
    char* base = ldsb + ((tt & 3) * 32768);
    #pragma unroll
    for (int l = 0; l < 4; ++l)
      gld16(p0[l] + off, base + ldsrel[l]);
  };

  i32x4 acc[8][4];
  #pragma unroll
  for (int m = 0; m < 8; ++m)
    #pragma unroll
    for (int n = 0; n < 4; ++n) acc[m][n] = (i32x4){0,0,0,0};

  const int swz  = (q ^ ((li >> 1) & 3)) * 16;
  const int arel = (wr*128 + li)*64 + swz;
  const int brel = 16384 + (wc*64 + li)*64 + swz;

  i32x4 a03[2][4], bv[2][4], a47[4];

  stage_tt(0); stage_tt(1); stage_tt(2);
  asm volatile("s_waitcnt vmcnt(8)" ::: "memory");
  __builtin_amdgcn_s_barrier();
  MEMFENCE;
  #pragma unroll
  for (int m = 0; m < 4; ++m) a03[0][m] = *(const i32x4*)(ldsb + arel + m*1024);
  #pragma unroll
  for (int n = 0; n < 4; ++n) bv[0][n]  = *(const i32x4*)(ldsb + brel + n*1024);

  for (int T2 = 0; T2 < 99; ++T2){
    #pragma unroll
    for (int half = 0; half < 2; ++half){
      const int T = 2*T2 + half;
      const char* buf  = ldsb + ((unsigned)T & 3u)*32768;
      const char* bufn = ldsb + ((unsigned)(T+1) & 3u)*32768;
      const int cur = half, nxt = half ^ 1;
      #pragma unroll
      for (int m = 0; m < 4; ++m) a47[m] = *(const i32x4*)(buf + arel + (m+4)*1024);
      MEMFENCE;
      asm volatile("s_waitcnt vmcnt(4)" ::: "memory");
      __builtin_amdgcn_s_barrier();
      MEMFENCE;
      if (T <= 196) stage_tt(T + 3);
      MEMFENCE;
      __builtin_amdgcn_s_setprio(1);
      #pragma unroll
      for (int m = 0; m < 4; ++m)
        #pragma unroll
        for (int n = 0; n < 4; ++n)
          acc[m][n] = __builtin_amdgcn_mfma_i32_16x16x64_i8(a03[cur][m], bv[cur][n], acc[m][n], 0, 0, 0);
      __builtin_amdgcn_s_setprio(0);
      // (fence removed: let scheduler interleave next-tile ds_reads with MFMA)
      #pragma unroll
      for (int m = 0; m < 4; ++m) a03[nxt][m] = *(const i32x4*)(bufn + arel + m*1024);
      #pragma unroll
      for (int n = 0; n < 4; ++n) bv[nxt][n]  = *(const i32x4*)(bufn + brel + n*1024);
      // (fence removed)
      __builtin_amdgcn_s_setprio(1);
      #pragma unroll
      for (int m = 0; m < 4; ++m)
        #pragma unroll
        for (int n = 0; n < 4; ++n)
          acc[m+4][n] = __builtin_amdgcn_mfma_i32_16x16x64_i8(a47[m], bv[cur][n], acc[m+4][n], 0, 0, 0);
      __builtin_amdgcn_s_setprio(0);
      MEMFENCE;
    }
  }
  // T = 198
  {
    const char* buf  = ldsb + (198 & 3)*32768;
    const char* bufn = ldsb + (199 & 3)*32768;
    #pragma unroll
    for (int m = 0; m < 4; ++m) a47[m] = *(const i32x4*)(buf + arel + (m+4)*1024);
    MEMFENCE;
    asm volatile("s_waitcnt vmcnt(0)" ::: "memory");
    __builtin_amdgcn_s_barrier();
    MEMFENCE;
    #pragma unroll
    for (int m = 0; m < 4; ++m)
      #pragma unroll
      for (int n = 0; n < 4; ++n)
        acc[m][n] = __builtin_amdgcn_mfma_i32_16x16x64_i8(a03[0][m], bv[0][n], acc[m][n], 0, 0, 0);
    #pragma unroll
    for (int m = 0; m < 4; ++m) a03[1][m] = *(const i32x4*)(bufn + arel + m*1024);
    #pragma unroll
    for (int n = 0; n < 4; ++n) bv[1][n]  = *(const i32x4*)(bufn + brel + n*1024);
    #pragma unroll
    for (int m = 0; m < 4; ++m)
      #pragma unroll
      for (int n = 0; n < 4; ++n)
        acc[m+4][n] = __builtin_amdgcn_mfma_i32_16x16x64_i8(a47[m], bv[0][n], acc[m+4][n], 0, 0, 0);
  }
  // T = 199
  {
    const char* buf = ldsb + (199 & 3)*32768;
    #pragma unroll
    for (int m = 0; m < 4; ++m) a47[m] = *(const i32x4*)(buf + arel + (m+4)*1024);
    #pragma unroll
    for (int m = 0; m < 4; ++m)
      #pragma unroll
      for (int n = 0; n < 4; ++n)
        acc[m][n] = __builtin_amdgcn_mfma_i32_16x16x64_i8(a03[1][m], bv[1][n], acc[m][n], 0, 0, 0);
    #pragma unroll
    for (int m = 0; m < 4; ++m)
      #pragma unroll
      for (int n = 0; n < 4; ++n)
        acc[m+4][n] = __builtin_amdgcn_mfma_i32_16x16x64_i8(a47[m], bv[1][n], acc[m+4][n], 0, 0, 0);
  }

  // epilogue: dequant i32 -> f32, pack bf16
  const int xq4 = (lane >> 4) << 2;
  const int cq  = wc*64 + (lane & 15);
  #pragma unroll
  for (int m = 0; m < 8; ++m){
    int p = wr*128 + m*16 + xq4;
    int y = y0 + (p >> 7), x = p & 127;
    #pragma unroll
    for (int n = 0; n < 4; ++n){
      int cp = cq + n*16;
      i32x4 a = acc[m][n];
      uint2 pk;
      pk.x = (unsigned)f2bf((float)a.x * INVQ) | ((unsigned)f2bf((float)a.y * INVQ) << 16);
      pk.y = (unsigned)f2bf((float)a.z * INVQ) | ((unsigned)f2bf((float)a.w * INVQ) << 16);
      *(uint2*)(spade + (((size_t)(b*256 + cp))*HH + y)*WW + x) = pk;
    }
  }
}

// ---------------- final: paired-pixel gather + blend + IN apply -----------
__global__ void k_final(const float* __restrict__ xin, const int* __restrict__ ids,
                        const float2* __restrict__ G, const unsigned short* __restrict__ spade,
                        const float* __restrict__ mean, const float* __restrict__ rstd,
                        const float* __restrict__ cgb, const float* __restrict__ cbb,
                        const float* __restrict__ sgb, const float* __restrict__ sbb,
                        const float* __restrict__ bgam, const float* __restrict__ bbet,
                        float* __restrict__ out){
  const int blk = blockIdx.x;
  const int b = blk >> 7, c = blk & 127;
  const int t = threadIdx.x;
  __shared__ float2 Gl2[500];                  // [tap][id] transposed
  for (int i = t; i < 500; i += 256){
    int j = i / 25, d = i - (i/25)*25;
    Gl2[d*20 + j] = G[((size_t)(b*CC + c))*500 + i];
  }
  __syncthreads();
  const float ga = 1.f/(1.f + __expf(-bgam[0]));
  const float ba = 1.f/(1.f + __expf(-bbet[0]));
  const float mn = mean[b*CC + c], rs = rstd[b*CC + c];
  const float cg = cgb[c], cb = cbb[c], sg = sgb[c], sb = sbb[c];
  const float* xp  = xin + (size_t)(b*CC + c)*NPIX;
  const unsigned short* spg = spade + (size_t)(b*256 + c)*NPIX;
  const unsigned short* spb = spade + (size_t)(b*256 + c + 128)*NPIX;
  float* op = out + (size_t)(b*CC + c)*NPIX;
  const int* idb = ids + b*PCELLS;
  for (int p2 = t; p2 < NPIX/2; p2 += 256){
    int p = p2*2;
    int y = p >> 7, x = p & 127;
    float ag0=0.f, ab0=0.f, ag1=0.f, ab1=0.f;
    #pragma unroll
    for (int dy = 0; dy < 5; ++dy){
      const int* row = idb + (y+dy)*HP + x;    // 8B-aligned (even offset)
      int2 v01 = *(const int2*)(row);
      int2 v23 = *(const int2*)(row + 2);
      int2 v45 = *(const int2*)(row + 4);
      int idv[6] = {v01.x, v01.y, v23.x, v23.y, v45.x, v45.y};
      #pragma unroll
      for (int dx = 0; dx < 5; ++dx){
        float2 g0 = Gl2[(dy*5+dx)*20 + idv[dx]];
        float2 g1 = Gl2[(dy*5+dx)*20 + idv[dx+1]];
        ag0 += g0.x; ab0 += g0.y;
        ag1 += g1.x; ab1 += g1.y;
      }
    }
    unsigned sg2 = *(const unsigned*)(spg + p);
    unsigned sb2 = *(const unsigned*)(spb + p);
    float2 xv = *(const float2*)(xp + p);
    float gf0 = ga*(ag0 + cg) + (1.f - ga)*(bflo(sg2) + sg);
    float bf0 = ba*(ab0 + cb) + (1.f - ba)*(bflo(sb2) + sb);
    float gf1 = ga*(ag1 + cg) + (1.f - ga)*(bfhi(sg2) + sg);
    float bf1 = ba*(ab1 + cb) + (1.f - ba)*(bfhi(sb2) + sb);
    float2 ov;
    ov.x = (xv.x - mn)*rs*(1.f + gf0) + bf0;
    ov.y = (xv.y - mn)*rs*(1.f + gf1) + bf1;
    *(float2*)(op + p) = ov;
  }
}

extern "C" void kernel_launch(void* const* d_in, const int* in_sizes, int n_in,
                              void* d_out, int out_size, void* d_ws, size_t ws_size,
                              hipStream_t stream){
  const float* x    = (const float*)d_in[0];
  const float* seg  = (const float*)d_in[1];
  const float* sty  = (const float*)d_in[2];
  const float* fcw  = (const float*)d_in[3];
  const float* fcb  = (const float*)d_in[4];
  const float* cgw  = (const float*)d_in[5];
  const float* cgb  = (const float*)d_in[6];
  const float* cbw  = (const float*)d_in[7];
  const float* cbb  = (const float*)d_in[8];
  const float* ssw  = (const float*)d_in[9];
  const float* ssb  = (const float*)d_in[10];
  const float* sgw  = (const float*)d_in[11];
  const float* sgb  = (const float*)d_in[12];
  const float* sbw  = (const float*)d_in[13];
  const float* sbb  = (const float*)d_in[14];
  const float* bgam = (const float*)d_in[15];
  const float* bbet = (const float*)d_in[16];
  float* out = (float*)d_out;

  char* ws = (char*)d_ws;
  size_t o = 0;
  auto alloc = [&](size_t n){ size_t r = o; o = (o + n + 255) & ~(size_t)255; return r; };
  float* mean          = (float*)(ws + alloc(512*4));
  float* rstd          = (float*)(ws + alloc(512*4));
  int*   ids           = (int*)  (ws + alloc((size_t)NCELL*4));
  float* mu            = (float*)(ws + alloc((size_t)BB*LL*SS*4));
  float2* G            = (float2*)(ws + alloc((size_t)BB*CC*500*8));
  short* Tt16          = (short*)(ws + alloc((size_t)20*25*SS*2));
  unsigned char* W2q   = (unsigned char*)(ws + alloc((size_t)256*12800));
  unsigned char* actv8 = (unsigned char*)(ws + alloc((size_t)NCELL*SS));
  unsigned short* spade= (unsigned short*)(ws + alloc((size_t)BB*256*NPIX*2));
  // bf16 Wt tables alias spade region (consumed by k_mid before k_conv writes it)
  unsigned short* Wtg16 = spade;
  unsigned short* Wtb16 = spade + (size_t)128*25*512;
  (void)o; (void)ws_size; (void)in_sizes; (void)n_in; (void)out_size; (void)sty;

  k_pre  <<<dim3(2373), dim3(256), 0, stream>>>(x, mean, rstd, seg, ids,
                                                sty, fcw, fcb, mu,
                                                cgw, cbw, Wtg16, Wtb16,
                                                ssw, Tt16, sgw, sbw, (unsigned*)W2q);
  k_mid  <<<dim3(2696), dim3(512), 0, stream>>>(mu, Wtg16, Wtb16, G,
                                                ids, Tt16, ssb, (uint2*)actv8);
  k_conv <<<dim3(256),  dim3(512), 0, stream>>>(actv8, W2q, spade);
  k_final<<<dim3(512),  dim3(256), 0, stream>>>(x, ids, G, spade, mean, rstd,
                                                cgb, cbb, sgb, sbb, bgam, bbet, out);
}